// Round 2
// baseline (111.002 us; speedup 1.0000x reference)
//
#include <hip/hip_runtime.h>
#include <stdint.h>
#include <stddef.h>

// MambaMesh random-walk + gather-recenter.  R11: walk-per-lane transpose.
// PRNG (bit-exact vs JAX partitionable Threefry, verified R1-R10, absmax 0.0):
//   split(key,n)[j]        = threefry2x32(key; 0, j)   (both output words)
//   random_bits(key,32,()) = xor-fold of threefry2x32(key; 0, 0)
// R10 post-mortem: halving VALU issue gave only -5%; VALUBusy 44% -> walk
// loop is stall-bound: ~11 DS ops/iter/wave on the shared LDS pipe + cross-
// lane (bpermute) latency + 7us serial key-chain prologue (dep-lat floor).
// R11 transposes: lane = walk (16 walks on 16 lanes of wave 0). All decision
// machinery becomes lane-local (no shuffles, no exec juggling); 9-11 DS ops
// now advance SIXTEEN walks. Codes precomputed lane=(walk,step) by all 256
// threads, packed 3b x10/word into 7 VGPRs per walk-lane (uniform-index
// ternary extract replaces per-iter ds_bpermute). seq -> padded u16 LDS
// (backtrack only); output gather inlined + 1-deep pipelined (no epilogue).
//   block = 256 thr (4 waves), 16 walks/block, 256 blocks, 1 block/CU.
//   LDS: table 120,000 + bitmaps 16x625x4=40,000 + seq 16x68x2=2,176
//        = 162,176 B (max 163,840). Keys/codes scratch live inside the
//        bitmap region before zeroing (keys [0..2047], codes [2048..2303]).

namespace {

__device__ __forceinline__ uint32_t rotl32(uint32_t x, int r) {
  return (x << r) | (x >> (32 - r));
}

// Threefry-2x32, 20 rounds — exactly JAX's threefry2x32_p.
__device__ __forceinline__ void tf2x32(uint32_t ka, uint32_t kb,
                                       uint32_t x0, uint32_t x1,
                                       uint32_t& o0, uint32_t& o1) {
  const uint32_t kc = ka ^ kb ^ 0x1BD11BDAu;
  x0 += ka; x1 += kb;
#define TF_R4(r0, r1, r2, r3)                          \
  x0 += x1; x1 = rotl32(x1, r0); x1 ^= x0;             \
  x0 += x1; x1 = rotl32(x1, r1); x1 ^= x0;             \
  x0 += x1; x1 = rotl32(x1, r2); x1 ^= x0;             \
  x0 += x1; x1 = rotl32(x1, r3); x1 ^= x0;
  TF_R4(13, 15, 26, 6)  x0 += kb; x1 += kc + 1u;
  TF_R4(17, 29, 16, 24) x0 += kc; x1 += ka + 2u;
  TF_R4(13, 15, 26, 6)  x0 += ka; x1 += kb + 3u;
  TF_R4(17, 29, 16, 24) x0 += kb; x1 += kc + 4u;
  TF_R4(13, 15, 26, 6)  x0 += kc; x1 += ka + 5u;
#undef TF_R4
  o0 = x0; o1 = x1;
}

// (hi, lo) bits of jax.random.randint(key, (), 0, span): span-independent.
__device__ __forceinline__ void randbits(uint32_t ka, uint32_t kb,
                                         uint32_t& hi, uint32_t& lo) {
  uint32_t s0a, s0b, s1a, s1b, h0, h1;
  tf2x32(ka, kb, 0u, 0u, s0a, s0b);   // split(key)[0]
  tf2x32(ka, kb, 0u, 1u, s1a, s1b);   // split(key)[1]
  tf2x32(s0a, s0b, 0u, 0u, h0, h1);
  hi = h0 ^ h1;
  tf2x32(s1a, s1b, 0u, 0u, h0, h1);
  lo = h0 ^ h1;
}

__device__ __forceinline__ uint32_t r_generic(uint32_t hi, uint32_t lo,
                                              uint32_t span) {
  uint32_t mult = 65536u % span;
  mult = (mult * mult) % span;
  return ((hi % span) * mult + (lo % span)) % span;
}

// pick code: r3 (span=3 result) in bits 0..1, r2 (span=2 result) in bit 2.
__device__ __forceinline__ uint32_t pick_code(uint32_t hi, uint32_t lo) {
  return ((hi % 3u + lo % 3u) % 3u) | ((lo & 1u) << 2);
}

constexpr int WPB = 16;       // walks per block (one per lane of wave 0)
constexpr int CH = 64;        // cached chain length (covers seq_len 63)
constexpr int NMAX = 20000;   // LDS-table capacity (rows)
constexpr int VISW = 625;     // bitmap words per walk = ceil(NMAX/32)
constexpr int THREADS = 256;  // 4 waves

__global__ __launch_bounds__(256) void walk_kernel(
    const float* __restrict__ xyz, const int* __restrict__ nbrs,
    const int* __restrict__ centers, const int* __restrict__ n_faces_p,
    const int* __restrict__ seq_len_p, float* __restrict__ out,
    int s0, int num_walks, int Lp1) {
  // 80,000 + 40,000 + 40,000 + 2,176 = 162,176 B
  __shared__ uint32_t nb01L[NMAX];          // n0 | n1<<16
  __shared__ uint16_t nb2L[NMAX];           // n2
  __shared__ uint32_t visL[WPB * VISW];     // bitmaps; scratch pre-zero
  __shared__ uint16_t seqL[WPB][CH + 4];    // +4 pad: spreads banks

  const int tid = threadIdx.x;
  const int wv = tid >> 6, lane = tid & 63;
  const int w0 = blockIdx.x * WPB;
  if (w0 >= num_walks) return;               // block-uniform

  const int N = *n_faces_p;
  const int L = *seq_len_p;
  const int B = s0 / (3 * N);
  const int G = num_walks / B;
  const bool lds_ok = (N <= NMAX) && (G % WPB == 0) && (L < CH);
  const int bb0 = w0 / G;                    // all 16 walks share a batch

  // ---- Phase A: wave 0 lanes<16 = key carry chains -> visL[0..2047];
  //      waves 1..3 = table staging (lds_ok only). ------------------------
  if (wv == 0) {
    if (lane < WPB && (w0 + lane) < num_walks) {
      uint32_t ka, kb;
      tf2x32(0u, 42u, 0u, (uint32_t)(w0 + lane), ka, kb);  // k_0
      visL[(lane * CH + 0) * 2 + 0] = ka;
      visL[(lane * CH + 0) * 2 + 1] = kb;
#pragma clang loop unroll(disable)
      for (int c2 = 1; c2 < CH; ++c2) {
        tf2x32(ka, kb, 0u, 0u, ka, kb);
        visL[(lane * CH + c2) * 2 + 0] = ka;
        visL[(lane * CH + c2) * 2 + 1] = kb;
      }
    }
  } else if (lds_ok) {
    const int* __restrict__ nbT = nbrs + (size_t)bb0 * N * 3;
    for (int r = tid - 64; r < N; r += (THREADS - 64)) {
      const int3 v = *reinterpret_cast<const int3*>(nbT + 3 * (size_t)r);
      nb01L[r] = (uint32_t)v.x | ((uint32_t)v.y << 16);
      nb2L[r]  = (uint16_t)v.z;
    }
  }
  __syncthreads();   // barrier 1: keys + table staged

  if (lds_ok) {
    // ---- Phase B: per-step codes, lane=(walk,step), all 256 threads -----
    uint8_t* const codesB = reinterpret_cast<uint8_t*>(&visL[2048]);
#pragma unroll
    for (int p = 0; p < (WPB * CH) / THREADS; ++p) {   // 4 pairs/thread
      const int pair = tid + THREADS * p;
      const int wk = pair >> 6, st = pair & 63;
      if ((w0 + wk) < num_walks) {
        const uint32_t ka = visL[(wk * CH + st) * 2 + 0];
        const uint32_t kb = visL[(wk * CH + st) * 2 + 1];
        uint32_t k1a, k1b, hi, lo;
        tf2x32(ka, kb, 0u, 1u, k1a, k1b);   // k1 = split(k,4)[1]
        randbits(k1a, k1b, hi, lo);
        codesB[wk * CH + st] = (uint8_t)pick_code(hi, lo);
      }
    }
    __syncthreads();   // barrier 2: codes ready

    // ---- Phase C: walker lanes pack codes -> 7 VGPRs; keep k_0 ----------
    const int w = w0 + lane;
    const bool walker = (wv == 0) && (lane < WPB) && (w < num_walks);
    uint32_t cw[7] = {0, 0, 0, 0, 0, 0, 0};
    uint32_t k0a = 0, k0b = 0;
    if (walker) {
      tf2x32(0u, 42u, 0u, (uint32_t)w, k0a, k0b);   // cheap k_0 recompute
      const uint32_t* cwd = &visL[2048 + lane * (CH / 4)];
#pragma unroll
      for (int t = 0; t < CH / 4; ++t) {
        const uint32_t wd = cwd[t];
#pragma unroll
        for (int b = 0; b < 4; ++b) {
          const int s = 4 * t + b;               // compile-time
          const uint32_t c3 = (wd >> (8 * b)) & 7u;
          cw[s / 10] |= c3 << (3 * (s % 10));    // constant indices only
        }
      }
    }
    __syncthreads();   // barrier 3: scratch reads done
    // ---- Phase D: zero bitmaps (all threads) ----------------------------
    for (int j = tid; j < WPB * VISW; j += THREADS) visL[j] = 0u;
    __syncthreads();   // barrier 4: bitmaps ready
    if (wv != 0) return;                       // waves 1-3 done

    // =================== wave 0: 16 lane-local walks =====================
    const float* __restrict__ xb = xyz + (size_t)bb0 * N * 3;
    const int f0 = walker ? centers[w] : 0;
    uint32_t* __restrict__ visW = visL + (walker ? lane : 0) * VISW;

    float cx = 0.f, cy = 0.f, cz = 0.f;
    if (walker) {
      cx = xb[3 * (size_t)f0 + 0];
      cy = xb[3 * (size_t)f0 + 1];
      cz = xb[3 * (size_t)f0 + 2];
      visW[(unsigned)f0 >> 5] = 1u << (f0 & 31);
      seqL[lane][0] = (uint16_t)f0;
      float3 z; z.x = 0.f; z.y = 0.f; z.z = 0.f;   // xyz[f0]-center == +0.0
      *reinterpret_cast<float3*>(out + (size_t)w * Lp1 * 3) = z;
    }

    // candidate state + 1-iter prefetch of rows and vis words
    const uint32_t p0 = nb01L[f0];
    int n0 = (int)(p0 & 0xffffu), n1 = (int)(p0 >> 16), n2 = (int)nb2L[f0];
    uint32_t pA01 = nb01L[n0], pB01 = nb01L[n1], pC01 = nb01L[n2];
    uint32_t pA2 = nb2L[n0], pB2 = nb2L[n1], pC2 = nb2L[n2];
    uint32_t wd0 = visW[(unsigned)n0 >> 5];
    uint32_t wd1 = visW[(unsigned)n1 >> 5];
    uint32_t wd2 = visW[(unsigned)n2 >> 5];

    int i = walker ? 1 : (L + 1);
    int bs = 1;
    int extc = 0; uint32_t extka = k0a, extkb = k0b;   // extka = k_extc
    bool pend = false; float3 pg; uint32_t ppos = 0;

    for (int c = 0;; ++c) {
      if (!__any(i <= L)) break;
      const bool act = (i <= L);

      // flush previous gather (loaded a full iter ago; before any splat)
      if (pend) {
        float3 v; v.x = pg.x - cx; v.y = pg.y - cy; v.z = pg.z - cz;
        *reinterpret_cast<float3*>(out + (size_t)ppos * 3) = v;
        pend = false;
      }

      const uint32_t u0 = ((wd0 >> (n0 & 31)) & 1u) ^ 1u;
      const uint32_t u1 = ((wd1 >> (n1 & 31)) & 1u) ^ 1u;
      const uint32_t u2 = ((wd2 >> (n2 & 31)) & 1u) ^ 1u;
      const uint32_t cnt = u0 + u1 + u2;

      uint32_t code;
      if (__builtin_expect(c < CH, 1)) {
        const int wi = c / 10;                    // uniform
        const int sh = 3 * (c - wi * 10);
        uint32_t cwv = cw[0];
        cwv = (wi == 1) ? cw[1] : cwv;  cwv = (wi == 2) ? cw[2] : cwv;
        cwv = (wi == 3) ? cw[3] : cwv;  cwv = (wi == 4) ? cw[4] : cwv;
        cwv = (wi == 5) ? cw[5] : cwv;  cwv = (wi == 6) ? cw[6] : cwv;
        code = (cwv >> sh) & 7u;
      } else {
        // live tree beyond cached steps (only after backtracks; uniform c)
        while (extc < c) { tf2x32(extka, extkb, 0u, 0u, extka, extkb); ++extc; }
        uint32_t k1a, k1b, hi, lo;
        tf2x32(extka, extkb, 0u, 1u, k1a, k1b);
        randbits(k1a, k1b, hi, lo);
        code = pick_code(hi, lo);
      }

      const bool need = act && (cnt == 0u);
      if (__builtin_expect(__any(need), 0)) {
        // ---- rare path (lane-local backtrack; bit-exact) ----
        while (extc < c) { tf2x32(extka, extkb, 0u, 0u, extka, extkb); ++extc; }
        const uint32_t kia = extka, kib = extkb;   // = k_c
        bool found = false; int ta = 0; int bsc = bs;
        if (need) {
          uint32_t kka, kkb;
          tf2x32(kia, kib, 0u, 2u, kka, kkb);      // k2
          while (!found && i > bsc) {
            uint32_t ca, cb, kpa, kpb;
            tf2x32(kka, kkb, 0u, 0u, ca, cb);
            tf2x32(kka, kkb, 0u, 1u, kpa, kpb);
            const int back = (int)seqL[lane][i - bsc - 1];
            const uint32_t pm = nb01L[back];
            const int m0 = (int)(pm & 0xffffu), m1 = (int)(pm >> 16);
            const int m2 = (int)nb2L[back];
            const uint32_t e0 = ((visW[(unsigned)m0 >> 5] >> (m0 & 31)) & 1u) ^ 1u;
            const uint32_t e1 = ((visW[(unsigned)m1 >> 5] >> (m1 & 31)) & 1u) ^ 1u;
            const uint32_t e2 = ((visW[(unsigned)m2 >> 5] >> (m2 & 31)) & 1u) ^ 1u;
            const uint32_t bc = e0 + e1 + e2;
            if (bc > 0) {
              uint32_t bhi, blo;
              randbits(kpa, kpb, bhi, blo);
              const uint32_t bcode = pick_code(bhi, blo);
              const uint32_t br3 = bcode & 3u, br2 = (bcode >> 2) & 1u;
              const uint32_t t2v = (bc == 3 ? br3 : (bc == 2 ? br2 : 0)) + 1;
              ta = (e0 == t2v) ? m0 : ((e0 + e1 == t2v) ? m1 : m2);
              found = true;
            } else {
              bsc += 2;
            }
            kka = ca; kkb = cb;
          }
        }
        int rnd = 0;
        if (need && !found) {
          uint32_t k3a, k3b, rhi, rlo;
          tf2x32(kia, kib, 0u, 3u, k3a, k3b);      // k3
          randbits(k3a, k3b, rhi, rlo);
          rnd = (int)r_generic(rhi, rlo, (uint32_t)N);
        }
        // common-path candidate for act && !need lanes
        const uint32_t r3 = code & 3u, r2 = (code >> 2) & 1u;
        const uint32_t tgt = (cnt == 3 ? r3 : (cnt == 2 ? r2 : 0)) + 1;
        const int selc = (u0 == tgt) ? 0 : ((u0 + u1 == tgt) ? 1 : 2);
        const int to_add_c = (selc == 0) ? n0 : ((selc == 1) ? n1 : n2);
        const uint32_t wselc = (selc == 0) ? wd0 : ((selc == 1) ? wd1 : wd2);

        const bool hit = need && found;
        const int to_add = need ? (found ? ta : rnd) : to_add_c;

        if (act) {
          uint32_t wdf = need ? visW[(unsigned)to_add >> 5] : wselc;
          visW[(unsigned)to_add >> 5] = wdf | (1u << (to_add & 31));
          if (hit) {
            const int i_new = i - bsc;
            const float3 p = *reinterpret_cast<const float3*>(
                xb + 3 * (size_t)to_add);
            float3 v; v.x = p.x - cx; v.y = p.y - cy; v.z = p.z - cz;
            for (int j = i_new; j < i; ++j) {
              seqL[lane][j] = (uint16_t)to_add;
              *reinterpret_cast<float3*>(
                  out + ((size_t)w * Lp1 + j) * 3) = v;
            }
            bs = bsc; i = i_new + 1;
          } else {
            seqL[lane][i] = (uint16_t)to_add;
            pg = *reinterpret_cast<const float3*>(xb + 3 * (size_t)to_add);
            pend = true; ppos = (uint32_t)(w * Lp1 + i);
            bs = 1; ++i;
          }
        }
        // next candidates: dependent row read (rare)
        const int rn = act ? to_add : 0;
        const uint32_t pr = nb01L[rn];
        const uint32_t pr2 = nb2L[rn];
        if (act) {
          n0 = (int)(pr & 0xffffu); n1 = (int)(pr >> 16); n2 = (int)pr2;
        }
      } else {
        // ---- common path: branch-lean, fully lane-local ----
        const uint32_t r3 = code & 3u, r2 = (code >> 2) & 1u;
        const uint32_t tgt = (cnt == 3 ? r3 : (cnt == 2 ? r2 : 0)) + 1;
        const int sel = (u0 == tgt) ? 0 : ((u0 + u1 == tgt) ? 1 : 2);
        const int to_add = (sel == 0) ? n0 : ((sel == 1) ? n1 : n2);
        const uint32_t wsel = (sel == 0) ? wd0 : ((sel == 1) ? wd1 : wd2);
        if (act) {
          // wsel includes last iter's write (reads issued after it in-order)
          visW[(unsigned)to_add >> 5] = wsel | (1u << (to_add & 31));
          seqL[lane][i] = (uint16_t)to_add;
          pg = *reinterpret_cast<const float3*>(xb + 3 * (size_t)to_add);
          pend = true; ppos = (uint32_t)(w * Lp1 + i);
          bs = 1; ++i;
          if (sel == 0)      { n0 = (int)(pA01 & 0xffffu); n1 = (int)(pA01 >> 16); n2 = (int)pA2; }
          else if (sel == 1) { n0 = (int)(pB01 & 0xffffu); n1 = (int)(pB01 >> 16); n2 = (int)pB2; }
          else               { n0 = (int)(pC01 & 0xffffu); n1 = (int)(pC01 >> 16); n2 = (int)pC2; }
        }
      }
      // prefetch rows + vis words for next iteration (after this iter's
      // bitmap write: in-order DS within wave -> values are fresh)
      pA01 = nb01L[n0]; pA2 = nb2L[n0];
      pB01 = nb01L[n1]; pB2 = nb2L[n1];
      pC01 = nb01L[n2]; pC2 = nb2L[n2];
      wd0 = visW[(unsigned)n0 >> 5];
      wd1 = visW[(unsigned)n1 >> 5];
      wd2 = visW[(unsigned)n2 >> 5];
    }
    // final flush
    if (pend) {
      float3 v; v.x = pg.x - cx; v.y = pg.y - cy; v.z = pg.z - cz;
      *reinterpret_cast<float3*>(out + (size_t)ppos * 3) = v;
    }
  } else {
    // ============ global-chase fallback (verified R5/R8/R10 logic) =======
    // 4 waves x 4 sequential full-wave walks; keys intact in visL scratch.
    for (int sub = 0; sub < 4; ++sub) {
      const int w = w0 + 4 * wv + sub;
      if (w >= num_walks) continue;          // wave-uniform
      const int bb = w / G;
      const int* __restrict__ nbG = nbrs + (size_t)bb * N * 3;
      const float* __restrict__ xb = xyz + (size_t)bb * N * 3;
      const int f0 = centers[w];
      const uint32_t mka = visL[((4 * wv + sub) * CH + lane) * 2 + 0];
      const uint32_t mkb = visL[((4 * wv + sub) * CH + lane) * 2 + 1];
      uint32_t mycode;
      {
        uint32_t k1a, k1b, hi, lo;
        tf2x32(mka, mkb, 0u, 1u, k1a, k1b);
        randbits(k1a, k1b, hi, lo);
        mycode = pick_code(hi, lo);
      }
      uint32_t extka = 0, extkb = 0;
      int extc = -1;
      auto get_key = [&](int idxk, uint32_t& ra, uint32_t& rb) {
        if (idxk < CH) {
          ra = (uint32_t)__shfl((int)mka, idxk);
          rb = (uint32_t)__shfl((int)mkb, idxk);
        } else {
          if (extc < 0) {
            extka = (uint32_t)__shfl((int)mka, CH - 1);
            extkb = (uint32_t)__shfl((int)mkb, CH - 1);
            extc = CH - 1;
          }
          while (extc < idxk) { tf2x32(extka, extkb, 0u, 0u, extka, extkb); ++extc; }
          ra = extka; rb = extkb;
        }
      };

      int seqr = (lane == 0) ? f0 : -1;
      uint32_t code_next = (uint32_t)__shfl((int)mycode, 0);
      int i = 1, bs = 1, c = 0;
      int hist  = (lane == 0) ? f0 : -1;
      int hist2 = -1;
      int3 row = *reinterpret_cast<const int3*>(nbG + 3 * (size_t)f0);
      while (i <= L) {
        const int idx = c; ++c;
        const bool deep = (idx >= CH);
        const uint32_t codeP = code_next;
        code_next = (uint32_t)__shfl((int)mycode, (c < CH) ? c : 0);

        const int n0 = row.x, n1 = row.y, n2 = row.z;
        int v0 = __any(hist == n0), v1 = __any(hist == n1), v2 = __any(hist == n2);
        if (deep) {
          v0 |= __any(hist2 == n0); v1 |= __any(hist2 == n1); v2 |= __any(hist2 == n2);
        }
        const int u0 = 1 - v0, u1 = 1 - v1, u2 = 1 - v2;
        const int cnt = u0 + u1 + u2;

        int to_add;
        bool hit = false;
        int bsf = bs;
        if (cnt > 0) {
          uint32_t code = codeP;
          if (deep) {
            uint32_t ia, ib, k1a, k1b, hi, lo;
            get_key(idx, ia, ib);
            tf2x32(ia, ib, 0u, 1u, k1a, k1b);
            randbits(k1a, k1b, hi, lo);
            code = pick_code(hi, lo);
          }
          const int r3 = (int)(code & 3u), r2 = (int)((code >> 2) & 1u);
          const int target = (cnt == 3 ? r3 : (cnt == 2 ? r2 : 0)) + 1;
          to_add = (u0 == target) ? n0 : ((u0 + u1 == target) ? n1 : n2);
        } else {
          uint32_t kia, kib;
          get_key(idx, kia, kib);
          uint32_t kka, kkb;
          tf2x32(kia, kib, 0u, 2u, kka, kkb);
          bool found = false;
          int ta = 0, bsc = bs;
          while (!found && i > bsc) {
            uint32_t ca, cb, kpa, kpb;
            tf2x32(kka, kkb, 0u, 0u, ca, cb);
            tf2x32(kka, kkb, 0u, 1u, kpa, kpb);
            const int back = __shfl(seqr, i - bsc - 1);
            const int3 br = *reinterpret_cast<const int3*>(nbG + 3 * (size_t)back);
            int w0m = __any(hist == br.x), w1m = __any(hist == br.y), w2m = __any(hist == br.z);
            if (deep) {
              w0m |= __any(hist2 == br.x); w1m |= __any(hist2 == br.y); w2m |= __any(hist2 == br.z);
            }
            const int e0 = 1 - w0m, e1 = 1 - w1m, e2 = 1 - w2m;
            const int bc = e0 + e1 + e2;
            if (bc > 0) {
              uint32_t bhi, blo;
              randbits(kpa, kpb, bhi, blo);
              const uint32_t bcode = pick_code(bhi, blo);
              const int r3 = (int)(bcode & 3u), r2 = (int)((bcode >> 2) & 1u);
              const int t2v = (bc == 3 ? r3 : (bc == 2 ? r2 : 0)) + 1;
              ta = (e0 == t2v) ? br.x : ((e0 + e1 == t2v) ? br.y : br.z);
              found = true;
            } else {
              bsc += 2;
            }
            kka = ca; kkb = cb;
          }
          if (found) {
            to_add = ta; hit = true; bsf = bsc;
          } else {
            uint32_t k3a, k3b, rhi, rlo;
            tf2x32(kia, kib, 0u, 3u, k3a, k3b);
            randbits(k3a, k3b, rhi, rlo);
            to_add = (int)r_generic(rhi, rlo, (uint32_t)N);
          }
        }

        int i_new, up;
        if (hit) { i_new = i - bsf; bs = bsf; up = i - 1; }
        else     { i_new = i;       bs = 1;   up = i; }
        seqr = (lane >= i_new && lane <= up) ? to_add : seqr;

        const int slot = idx + 1;
        if (slot < CH)          hist  = (lane == slot)      ? to_add : hist;
        else if (slot < 2 * CH) hist2 = (lane == slot - CH) ? to_add : hist2;

        i = i_new + 1;
        row = *reinterpret_cast<const int3*>(nbG + 3 * (size_t)to_add);
      }

      const float cx = xb[3 * (size_t)f0 + 0];
      const float cy = xb[3 * (size_t)f0 + 1];
      const float cz = xb[3 * (size_t)f0 + 2];
      if (lane < Lp1) {
        const int node = seqr;
        float3 v;
        v.x = xb[3 * (size_t)node + 0] - cx;
        v.y = xb[3 * (size_t)node + 1] - cy;
        v.z = xb[3 * (size_t)node + 2] - cz;
        *reinterpret_cast<float3*>(out + ((size_t)w * Lp1 + lane) * 3) = v;
      }
    }
  }
}

}  // namespace

extern "C" void kernel_launch(void* const* d_in, const int* in_sizes, int n_in,
                              void* d_out, int out_size, void* d_ws, size_t ws_size,
                              hipStream_t stream) {
  const float* xyz     = (const float*)d_in[0];
  const int*   nbrs    = (const int*)d_in[1];
  const int*   centers = (const int*)d_in[2];
  const int*   n_faces = (const int*)d_in[3];
  const int*   seq_len = (const int*)d_in[4];
  float* out = (float*)d_out;

  const int s0 = in_sizes[0];                  // B*N*3
  const int num_walks = in_sizes[2];           // B*G
  const int Lp1 = out_size / (3 * num_walks);  // seq_len+1

  const int blocks = (num_walks + WPB - 1) / WPB;
  walk_kernel<<<blocks, THREADS, 0, stream>>>(
      xyz, nbrs, centers, n_faces, seq_len, out, s0, num_walks, Lp1);
}

// Round 4
// 105.751 us; speedup vs baseline: 1.0497x; 1.0497x over previous
//
#include <hip/hip_runtime.h>
#include <stdint.h>
#include <stddef.h>

// MambaMesh random-walk + gather-recenter.  R12b: 2 walker lanes x 8 waves.
// (Resubmit of R12 — previous bench died of container infra failure, not a
// kernel verdict. Code audit found no OOB/race/deadlock hazard.)
// PRNG (bit-exact vs JAX partitionable Threefry, verified R1-R11, absmax 0.0):
//   split(key,n)[j]        = threefry2x32(key; 0, j)   (both output words)
//   random_bits(key,32,()) = xor-fold of threefry2x32(key; 0, 0)
// R11 post-mortem: walk-per-lane in ONE wave = 2x regression (54us, VALUBusy
// 12%, chain ~1670cyc/iter fully exposed: 1 wave/CU, 16-addr scatter DS at
// ~5.7x conflict cost, global gather in-loop). R12 keeps R11's lane-local
// decision body (no shuffles/cross-lane) but restores TLP: 8 waves/block,
// each wave owns TWO walks (lanes 0 and 32). 2 waves/SIMD hide DS latency;
// scatter reads have <=2 addrs/instr (2-way aliasing free, m136); the
// global gather/store moves out of the loop into a block-wide epilogue
// reading seqL (all 512 threads, coalesced stores).
//   block = 512 thr (8 waves), 16 walks/block, 256 blocks, 1 block/CU.
//   LDS: table 120,000 + bitmaps 40,000 + seq 2,176 + centers 192
//        = 162,368 B (max 163,840). Keys/codes scratch reuse the bitmap
//        region before zeroing (keys words [0..2047], codes [2048..2303]).

namespace {

__device__ __forceinline__ uint32_t rotl32(uint32_t x, int r) {
  return (x << r) | (x >> (32 - r));
}

// Threefry-2x32, 20 rounds — exactly JAX's threefry2x32_p.
__device__ __forceinline__ void tf2x32(uint32_t ka, uint32_t kb,
                                       uint32_t x0, uint32_t x1,
                                       uint32_t& o0, uint32_t& o1) {
  const uint32_t kc = ka ^ kb ^ 0x1BD11BDAu;
  x0 += ka; x1 += kb;
#define TF_R4(r0, r1, r2, r3)                          \
  x0 += x1; x1 = rotl32(x1, r0); x1 ^= x0;             \
  x0 += x1; x1 = rotl32(x1, r1); x1 ^= x0;             \
  x0 += x1; x1 = rotl32(x1, r2); x1 ^= x0;             \
  x0 += x1; x1 = rotl32(x1, r3); x1 ^= x0;
  TF_R4(13, 15, 26, 6)  x0 += kb; x1 += kc + 1u;
  TF_R4(17, 29, 16, 24) x0 += kc; x1 += ka + 2u;
  TF_R4(13, 15, 26, 6)  x0 += ka; x1 += kb + 3u;
  TF_R4(17, 29, 16, 24) x0 += kb; x1 += kc + 4u;
  TF_R4(13, 15, 26, 6)  x0 += kc; x1 += ka + 5u;
#undef TF_R4
  o0 = x0; o1 = x1;
}

// (hi, lo) bits of jax.random.randint(key, (), 0, span): span-independent.
__device__ __forceinline__ void randbits(uint32_t ka, uint32_t kb,
                                         uint32_t& hi, uint32_t& lo) {
  uint32_t s0a, s0b, s1a, s1b, h0, h1;
  tf2x32(ka, kb, 0u, 0u, s0a, s0b);   // split(key)[0]
  tf2x32(ka, kb, 0u, 1u, s1a, s1b);   // split(key)[1]
  tf2x32(s0a, s0b, 0u, 0u, h0, h1);
  hi = h0 ^ h1;
  tf2x32(s1a, s1b, 0u, 0u, h0, h1);
  lo = h0 ^ h1;
}

__device__ __forceinline__ uint32_t r_generic(uint32_t hi, uint32_t lo,
                                              uint32_t span) {
  uint32_t mult = 65536u % span;
  mult = (mult * mult) % span;
  return ((hi % span) * mult + (lo % span)) % span;
}

// pick code: r3 (span=3 result) in bits 0..1, r2 (span=2 result) in bit 2.
__device__ __forceinline__ uint32_t pick_code(uint32_t hi, uint32_t lo) {
  return ((hi % 3u + lo % 3u) % 3u) | ((lo & 1u) << 2);
}

constexpr int WPB = 16;       // walks per block (2 per wave)
constexpr int CH = 64;        // cached chain length (covers seq_len 63)
constexpr int NMAX = 20000;   // LDS-table capacity (rows)
constexpr int VISW = 625;     // bitmap words per walk = ceil(NMAX/32)
constexpr int THREADS = 512;  // 8 waves

__global__ __launch_bounds__(512) void walk_kernel(
    const float* __restrict__ xyz, const int* __restrict__ nbrs,
    const int* __restrict__ centers, const int* __restrict__ n_faces_p,
    const int* __restrict__ seq_len_p, float* __restrict__ out,
    int s0, int num_walks, int Lp1) {
  // 80,000 + 40,000 + 40,000 + 2,176 + 192 = 162,368 B
  __shared__ uint32_t nb01L[NMAX];          // n0 | n1<<16
  __shared__ uint16_t nb2L[NMAX];           // n2
  __shared__ uint32_t visL[WPB * VISW];     // bitmaps; scratch pre-zero
  __shared__ uint16_t seqL[WPB][CH + 4];    // +4 pad
  __shared__ float cenL[WPB][3];            // center xyz per walk

  const int tid = threadIdx.x;
  const int wv = tid >> 6, lane = tid & 63;
  const int w0 = blockIdx.x * WPB;
  if (w0 >= num_walks) return;               // block-uniform

  const int N = *n_faces_p;
  const int L = *seq_len_p;
  const int B = s0 / (3 * N);
  const int G = num_walks / B;
  const bool lds_ok = (N <= NMAX) && (G % WPB == 0) && (L < CH);
  const int bb0 = w0 / G;                    // all 16 walks share a batch

  // ---- Phase A: wave 0 lanes<16 = key carry chains -> visL[0..2047];
  //      waves 1..7 = table staging (lds_ok only). ------------------------
  if (wv == 0) {
    if (lane < WPB && (w0 + lane) < num_walks) {
      uint32_t ka, kb;
      tf2x32(0u, 42u, 0u, (uint32_t)(w0 + lane), ka, kb);  // k_0
      visL[(lane * CH + 0) * 2 + 0] = ka;
      visL[(lane * CH + 0) * 2 + 1] = kb;
#pragma clang loop unroll(disable)
      for (int c2 = 1; c2 < CH; ++c2) {
        tf2x32(ka, kb, 0u, 0u, ka, kb);
        visL[(lane * CH + c2) * 2 + 0] = ka;
        visL[(lane * CH + c2) * 2 + 1] = kb;
      }
    }
  } else if (lds_ok) {
    const int* __restrict__ nbT = nbrs + (size_t)bb0 * N * 3;
    for (int r = tid - 64; r < N; r += (THREADS - 64)) {
      const int3 v = *reinterpret_cast<const int3*>(nbT + 3 * (size_t)r);
      nb01L[r] = (uint32_t)v.x | ((uint32_t)v.y << 16);
      nb2L[r]  = (uint16_t)v.z;
    }
  }
  __syncthreads();   // barrier 1: keys + table staged

  if (lds_ok) {
    const float* __restrict__ xb = xyz + (size_t)bb0 * N * 3;
    // ---- Phase B: per-step codes, (walk,step) pairs over all threads ----
    uint8_t* const codesB = reinterpret_cast<uint8_t*>(&visL[2048]);
#pragma unroll
    for (int p = 0; p < (WPB * CH) / THREADS; ++p) {   // 2 pairs/thread
      const int pair = tid + THREADS * p;
      const int wk = pair >> 6, st = pair & 63;
      if ((w0 + wk) < num_walks) {
        const uint32_t ka = visL[(wk * CH + st) * 2 + 0];
        const uint32_t kb = visL[(wk * CH + st) * 2 + 1];
        uint32_t k1a, k1b, hi, lo;
        tf2x32(ka, kb, 0u, 1u, k1a, k1b);   // k1 = split(k,4)[1]
        randbits(k1a, k1b, hi, lo);
        codesB[wk * CH + st] = (uint8_t)pick_code(hi, lo);
      }
    }
    // centers -> cenL (16 threads; overlaps codes work of others)
    if (tid < WPB && (w0 + tid) < num_walks) {
      const int f0t = centers[w0 + tid];
      cenL[tid][0] = xb[3 * (size_t)f0t + 0];
      cenL[tid][1] = xb[3 * (size_t)f0t + 1];
      cenL[tid][2] = xb[3 * (size_t)f0t + 2];
    }
    __syncthreads();   // barrier 2: codes + centers ready

    // ---- Phase C: walker lanes (0 and 32 of each wave) pack codes -------
    const int kw = 2 * wv + (lane >> 5);     // walk slot for this half
    const int w = w0 + kw;
    const bool walker = ((lane & 31) == 0) && (w < num_walks);
    uint32_t cw[7] = {0, 0, 0, 0, 0, 0, 0};
    uint32_t k0a = 0, k0b = 0;
    if (walker) {
      tf2x32(0u, 42u, 0u, (uint32_t)w, k0a, k0b);   // cheap k_0 recompute
      const uint32_t* cwd = &visL[2048 + kw * (CH / 4)];
#pragma unroll
      for (int t = 0; t < CH / 4; ++t) {
        const uint32_t wd = cwd[t];
#pragma unroll
        for (int b = 0; b < 4; ++b) {
          const int s = 4 * t + b;               // compile-time
          const uint32_t c3 = (wd >> (8 * b)) & 7u;
          cw[s / 10] |= c3 << (3 * (s % 10));    // constant indices only
        }
      }
    }
    __syncthreads();   // barrier 3: scratch reads done
    // ---- Phase D: zero bitmaps (all threads) ----------------------------
    for (int j = tid; j < WPB * VISW; j += THREADS) visL[j] = 0u;
    __syncthreads();   // barrier 4: bitmaps ready

    // =================== 8 waves x 2 lane-local walks ====================
    const int f0 = walker ? centers[w] : 0;
    uint32_t* __restrict__ visW = visL + (walker ? kw : 0) * VISW;

    if (walker) {
      visW[(unsigned)f0 >> 5] = 1u << (f0 & 31);
      seqL[kw][0] = (uint16_t)f0;
    }

    // candidate state + 1-iter prefetch of rows and vis words
    const uint32_t p0 = nb01L[f0];
    int n0 = (int)(p0 & 0xffffu), n1 = (int)(p0 >> 16), n2 = (int)nb2L[f0];
    uint32_t pA01 = nb01L[n0], pB01 = nb01L[n1], pC01 = nb01L[n2];
    uint32_t pA2 = nb2L[n0], pB2 = nb2L[n1], pC2 = nb2L[n2];
    uint32_t wd0 = visW[(unsigned)n0 >> 5];
    uint32_t wd1 = visW[(unsigned)n1 >> 5];
    uint32_t wd2 = visW[(unsigned)n2 >> 5];

    int i = walker ? 1 : (L + 1);
    int bs = 1;
    int extc = 0; uint32_t extka = k0a, extkb = k0b;   // extka = k_extc

    for (int c = 0;; ++c) {
      if (!__any(i <= L)) break;
      const bool act = (i <= L);

      const uint32_t u0 = ((wd0 >> (n0 & 31)) & 1u) ^ 1u;
      const uint32_t u1 = ((wd1 >> (n1 & 31)) & 1u) ^ 1u;
      const uint32_t u2 = ((wd2 >> (n2 & 31)) & 1u) ^ 1u;
      const uint32_t cnt = u0 + u1 + u2;

      uint32_t code;
      if (__builtin_expect(c < CH, 1)) {
        const int wi = c / 10;                    // uniform
        const int sh = 3 * (c - wi * 10);
        uint32_t cwv = cw[0];
        cwv = (wi == 1) ? cw[1] : cwv;  cwv = (wi == 2) ? cw[2] : cwv;
        cwv = (wi == 3) ? cw[3] : cwv;  cwv = (wi == 4) ? cw[4] : cwv;
        cwv = (wi == 5) ? cw[5] : cwv;  cwv = (wi == 6) ? cw[6] : cwv;
        code = (cwv >> sh) & 7u;
      } else {
        // live tree beyond cached steps (only after backtracks; uniform c)
        while (extc < c) { tf2x32(extka, extkb, 0u, 0u, extka, extkb); ++extc; }
        uint32_t k1a, k1b, hi, lo;
        tf2x32(extka, extkb, 0u, 1u, k1a, k1b);
        randbits(k1a, k1b, hi, lo);
        code = pick_code(hi, lo);
      }

      const bool need = act && (cnt == 0u);
      if (__builtin_expect(__any(need), 0)) {
        // ---- rare path (lane-local backtrack; bit-exact) ----
        while (extc < c) { tf2x32(extka, extkb, 0u, 0u, extka, extkb); ++extc; }
        const uint32_t kia = extka, kib = extkb;   // = k_c
        bool found = false; int ta = 0; int bsc = bs;
        if (need) {
          uint32_t kka, kkb;
          tf2x32(kia, kib, 0u, 2u, kka, kkb);      // k2
          while (!found && i > bsc) {
            uint32_t ca, cb, kpa, kpb;
            tf2x32(kka, kkb, 0u, 0u, ca, cb);
            tf2x32(kka, kkb, 0u, 1u, kpa, kpb);
            const int back = (int)seqL[kw][i - bsc - 1];
            const uint32_t pm = nb01L[back];
            const int m0 = (int)(pm & 0xffffu), m1 = (int)(pm >> 16);
            const int m2 = (int)nb2L[back];
            const uint32_t e0 = ((visW[(unsigned)m0 >> 5] >> (m0 & 31)) & 1u) ^ 1u;
            const uint32_t e1 = ((visW[(unsigned)m1 >> 5] >> (m1 & 31)) & 1u) ^ 1u;
            const uint32_t e2 = ((visW[(unsigned)m2 >> 5] >> (m2 & 31)) & 1u) ^ 1u;
            const uint32_t bc = e0 + e1 + e2;
            if (bc > 0) {
              uint32_t bhi, blo;
              randbits(kpa, kpb, bhi, blo);
              const uint32_t bcode = pick_code(bhi, blo);
              const uint32_t br3 = bcode & 3u, br2 = (bcode >> 2) & 1u;
              const uint32_t t2v = (bc == 3 ? br3 : (bc == 2 ? br2 : 0)) + 1;
              ta = (e0 == t2v) ? m0 : ((e0 + e1 == t2v) ? m1 : m2);
              found = true;
            } else {
              bsc += 2;
            }
            kka = ca; kkb = cb;
          }
        }
        int rnd = 0;
        if (need && !found) {
          uint32_t k3a, k3b, rhi, rlo;
          tf2x32(kia, kib, 0u, 3u, k3a, k3b);      // k3
          randbits(k3a, k3b, rhi, rlo);
          rnd = (int)r_generic(rhi, rlo, (uint32_t)N);
        }
        // common-path candidate for act && !need lanes
        const uint32_t r3 = code & 3u, r2 = (code >> 2) & 1u;
        const uint32_t tgt = (cnt == 3 ? r3 : (cnt == 2 ? r2 : 0)) + 1;
        const int selc = (u0 == tgt) ? 0 : ((u0 + u1 == tgt) ? 1 : 2);
        const int to_add_c = (selc == 0) ? n0 : ((selc == 1) ? n1 : n2);
        const uint32_t wselc = (selc == 0) ? wd0 : ((selc == 1) ? wd1 : wd2);

        const bool hit = need && found;
        const int to_add = need ? (found ? ta : rnd) : to_add_c;

        if (act) {
          uint32_t wdf = need ? visW[(unsigned)to_add >> 5] : wselc;
          visW[(unsigned)to_add >> 5] = wdf | (1u << (to_add & 31));
          if (hit) {
            const int i_new = i - bsc;
            for (int j = i_new; j < i; ++j) seqL[kw][j] = (uint16_t)to_add;
            bs = bsc; i = i_new + 1;
          } else {
            seqL[kw][i] = (uint16_t)to_add;
            bs = 1; ++i;
          }
        }
        // next candidates: dependent row read (rare)
        const int rn = act ? to_add : 0;
        const uint32_t pr = nb01L[rn];
        const uint32_t pr2 = nb2L[rn];
        if (act) {
          n0 = (int)(pr & 0xffffu); n1 = (int)(pr >> 16); n2 = (int)pr2;
        }
      } else {
        // ---- common path: branch-lean, fully lane-local ----
        const uint32_t r3 = code & 3u, r2 = (code >> 2) & 1u;
        const uint32_t tgt = (cnt == 3 ? r3 : (cnt == 2 ? r2 : 0)) + 1;
        const int sel = (u0 == tgt) ? 0 : ((u0 + u1 == tgt) ? 1 : 2);
        const int to_add = (sel == 0) ? n0 : ((sel == 1) ? n1 : n2);
        const uint32_t wsel = (sel == 0) ? wd0 : ((sel == 1) ? wd1 : wd2);
        if (act) {
          // wsel includes last iter's write (reads issued after it in-order)
          visW[(unsigned)to_add >> 5] = wsel | (1u << (to_add & 31));
          seqL[kw][i] = (uint16_t)to_add;
          bs = 1; ++i;
          if (sel == 0)      { n0 = (int)(pA01 & 0xffffu); n1 = (int)(pA01 >> 16); n2 = (int)pA2; }
          else if (sel == 1) { n0 = (int)(pB01 & 0xffffu); n1 = (int)(pB01 >> 16); n2 = (int)pB2; }
          else               { n0 = (int)(pC01 & 0xffffu); n1 = (int)(pC01 >> 16); n2 = (int)pC2; }
        }
      }
      // prefetch rows + vis words for next iteration (after this iter's
      // bitmap write: in-order DS within wave -> values are fresh)
      pA01 = nb01L[n0]; pA2 = nb2L[n0];
      pB01 = nb01L[n1]; pB2 = nb2L[n1];
      pC01 = nb01L[n2]; pC2 = nb2L[n2];
      wd0 = visW[(unsigned)n0 >> 5];
      wd1 = visW[(unsigned)n1 >> 5];
      wd2 = visW[(unsigned)n2 >> 5];
    }

    __syncthreads();   // barrier 5: all walks complete, seqL final

    // ---- Epilogue: block-wide gather-recenter from seqL -----------------
    const int items = WPB * Lp1;
    for (int idx = tid; idx < items; idx += THREADS) {
      const int wl = idx / Lp1;
      const int p = idx - wl * Lp1;
      const int ww = w0 + wl;
      if (ww < num_walks) {
        const int node = (int)seqL[wl][p];
        const float* xr = xb + 3 * (size_t)node;
        float3 v;
        v.x = xr[0] - cenL[wl][0];
        v.y = xr[1] - cenL[wl][1];
        v.z = xr[2] - cenL[wl][2];
        *reinterpret_cast<float3*>(out + ((size_t)ww * Lp1 + p) * 3) = v;
      }
    }
  } else {
    // ============ global-chase fallback (verified R5/R8/R10 logic) =======
    // 8 waves x 2 sequential full-wave walks; keys intact in visL scratch.
    for (int sub = 0; sub < 2; ++sub) {
      const int w = w0 + 2 * wv + sub;
      if (w >= num_walks) continue;          // wave-uniform
      const int bb = w / G;
      const int* __restrict__ nbG = nbrs + (size_t)bb * N * 3;
      const float* __restrict__ xb = xyz + (size_t)bb * N * 3;
      const int f0 = centers[w];
      const uint32_t mka = visL[((2 * wv + sub) * CH + lane) * 2 + 0];
      const uint32_t mkb = visL[((2 * wv + sub) * CH + lane) * 2 + 1];
      uint32_t mycode;
      {
        uint32_t k1a, k1b, hi, lo;
        tf2x32(mka, mkb, 0u, 1u, k1a, k1b);
        randbits(k1a, k1b, hi, lo);
        mycode = pick_code(hi, lo);
      }
      uint32_t extka = 0, extkb = 0;
      int extc = -1;
      auto get_key = [&](int idxk, uint32_t& ra, uint32_t& rb) {
        if (idxk < CH) {
          ra = (uint32_t)__shfl((int)mka, idxk);
          rb = (uint32_t)__shfl((int)mkb, idxk);
        } else {
          if (extc < 0) {
            extka = (uint32_t)__shfl((int)mka, CH - 1);
            extkb = (uint32_t)__shfl((int)mkb, CH - 1);
            extc = CH - 1;
          }
          while (extc < idxk) { tf2x32(extka, extkb, 0u, 0u, extka, extkb); ++extc; }
          ra = extka; rb = extkb;
        }
      };

      int seqr = (lane == 0) ? f0 : -1;
      uint32_t code_next = (uint32_t)__shfl((int)mycode, 0);
      int i = 1, bs = 1, c = 0;
      int hist  = (lane == 0) ? f0 : -1;
      int hist2 = -1;
      int3 row = *reinterpret_cast<const int3*>(nbG + 3 * (size_t)f0);
      while (i <= L) {
        const int idx = c; ++c;
        const bool deep = (idx >= CH);
        const uint32_t codeP = code_next;
        code_next = (uint32_t)__shfl((int)mycode, (c < CH) ? c : 0);

        const int n0 = row.x, n1 = row.y, n2 = row.z;
        int v0 = __any(hist == n0), v1 = __any(hist == n1), v2 = __any(hist == n2);
        if (deep) {
          v0 |= __any(hist2 == n0); v1 |= __any(hist2 == n1); v2 |= __any(hist2 == n2);
        }
        const int u0 = 1 - v0, u1 = 1 - v1, u2 = 1 - v2;
        const int cnt = u0 + u1 + u2;

        int to_add;
        bool hit = false;
        int bsf = bs;
        if (cnt > 0) {
          uint32_t code = codeP;
          if (deep) {
            uint32_t ia, ib, k1a, k1b, hi, lo;
            get_key(idx, ia, ib);
            tf2x32(ia, ib, 0u, 1u, k1a, k1b);
            randbits(k1a, k1b, hi, lo);
            code = pick_code(hi, lo);
          }
          const int r3 = (int)(code & 3u), r2 = (int)((code >> 2) & 1u);
          const int target = (cnt == 3 ? r3 : (cnt == 2 ? r2 : 0)) + 1;
          to_add = (u0 == target) ? n0 : ((u0 + u1 == target) ? n1 : n2);
        } else {
          uint32_t kia, kib;
          get_key(idx, kia, kib);
          uint32_t kka, kkb;
          tf2x32(kia, kib, 0u, 2u, kka, kkb);
          bool found = false;
          int ta = 0, bsc = bs;
          while (!found && i > bsc) {
            uint32_t ca, cb, kpa, kpb;
            tf2x32(kka, kkb, 0u, 0u, ca, cb);
            tf2x32(kka, kkb, 0u, 1u, kpa, kpb);
            const int back = __shfl(seqr, i - bsc - 1);
            const int3 br = *reinterpret_cast<const int3*>(nbG + 3 * (size_t)back);
            int w0m = __any(hist == br.x), w1m = __any(hist == br.y), w2m = __any(hist == br.z);
            if (deep) {
              w0m |= __any(hist2 == br.x); w1m |= __any(hist2 == br.y); w2m |= __any(hist2 == br.z);
            }
            const int e0 = 1 - w0m, e1 = 1 - w1m, e2 = 1 - w2m;
            const int bc = e0 + e1 + e2;
            if (bc > 0) {
              uint32_t bhi, blo;
              randbits(kpa, kpb, bhi, blo);
              const uint32_t bcode = pick_code(bhi, blo);
              const int r3 = (int)(bcode & 3u), r2 = (int)((bcode >> 2) & 1u);
              const int t2v = (bc == 3 ? r3 : (bc == 2 ? r2 : 0)) + 1;
              ta = (e0 == t2v) ? br.x : ((e0 + e1 == t2v) ? br.y : br.z);
              found = true;
            } else {
              bsc += 2;
            }
            kka = ca; kkb = cb;
          }
          if (found) {
            to_add = ta; hit = true; bsf = bsc;
          } else {
            uint32_t k3a, k3b, rhi, rlo;
            tf2x32(kia, kib, 0u, 3u, k3a, k3b);
            randbits(k3a, k3b, rhi, rlo);
            to_add = (int)r_generic(rhi, rlo, (uint32_t)N);
          }
        }

        int i_new, up;
        if (hit) { i_new = i - bsf; bs = bsf; up = i - 1; }
        else     { i_new = i;       bs = 1;   up = i; }
        seqr = (lane >= i_new && lane <= up) ? to_add : seqr;

        const int slot = idx + 1;
        if (slot < CH)          hist  = (lane == slot)      ? to_add : hist;
        else if (slot < 2 * CH) hist2 = (lane == slot - CH) ? to_add : hist2;

        i = i_new + 1;
        row = *reinterpret_cast<const int3*>(nbG + 3 * (size_t)to_add);
      }

      const float cx = xb[3 * (size_t)f0 + 0];
      const float cy = xb[3 * (size_t)f0 + 1];
      const float cz = xb[3 * (size_t)f0 + 2];
      if (lane < Lp1) {
        const int node = seqr;
        float3 v;
        v.x = xb[3 * (size_t)node + 0] - cx;
        v.y = xb[3 * (size_t)node + 1] - cy;
        v.z = xb[3 * (size_t)node + 2] - cz;
        *reinterpret_cast<float3*>(out + ((size_t)w * Lp1 + lane) * 3) = v;
      }
    }
  }
}

}  // namespace

extern "C" void kernel_launch(void* const* d_in, const int* in_sizes, int n_in,
                              void* d_out, int out_size, void* d_ws, size_t ws_size,
                              hipStream_t stream) {
  const float* xyz     = (const float*)d_in[0];
  const int*   nbrs    = (const int*)d_in[1];
  const int*   centers = (const int*)d_in[2];
  const int*   n_faces = (const int*)d_in[3];
  const int*   seq_len = (const int*)d_in[4];
  float* out = (float*)d_out;

  const int s0 = in_sizes[0];                  // B*N*3
  const int num_walks = in_sizes[2];           // B*G
  const int Lp1 = out_size / (3 * num_walks);  // seq_len+1

  const int blocks = (num_walks + WPB - 1) / WPB;
  walk_kernel<<<blocks, THREADS, 0, stream>>>(
      xyz, nbrs, centers, n_faces, seq_len, out, s0, num_walks, Lp1);
}

// Round 5
// 97.606 us; speedup vs baseline: 1.1372x; 1.0834x over previous
//
#include <hip/hip_runtime.h>
#include <stdint.h>
#include <stddef.h>

// MambaMesh random-walk + gather-recenter.  R13: pristine branchless fast loop.
// PRNG (bit-exact vs JAX partitionable Threefry, verified R1-R12, absmax 0.0):
//   split(key,n)[j]        = threefry2x32(key; 0, j)   (both output words)
//   random_bits(key,32,()) = xor-fold of threefry2x32(key; 0, 0)
// R12 post-mortem: walk wall-clock == 63 x ~1300cyc/iter ACROSS R9/R10/R12
// (different instr counts, different wave counts) -> per-iteration SERIAL
// chain, dominated not by DS latency (~120) + VALU deps (~100) but by
// control machinery: ~8 exec save/restore regions, 3 v_cmp->vcc->s_cbranch
// round trips, i/bs bookkeeping, conservative scheduling around the in-loop
// rare path. R13: backtracks are ~never taken on this input (P~3e-8/step),
// so run a FIXED-TRIP branchless loop (i==c+1, bs==1, no act predication,
// no c<CH branch, ONE __any exit check). If __any(cnt==0&&walker) fires,
// the wave falls into the R12 general loop (verified verbatim) for the
// remaining steps -> bit-exact for ALL inputs. Writes stay guarded by a
// loop-invariant 2-lane exec mask. Bitmap zeroing via b128.
//   block = 512 thr (8 waves), walker lanes 0/32, 16 walks/block, 256 blocks.
//   LDS: table 120,000 + bitmaps 40,000 + seq 2,176 + centers 192
//        = 162,368 B. Keys scratch visL[0..2047], codes visL[2048..2303].

namespace {

__device__ __forceinline__ uint32_t rotl32(uint32_t x, int r) {
  return (x << r) | (x >> (32 - r));
}

// Threefry-2x32, 20 rounds — exactly JAX's threefry2x32_p.
__device__ __forceinline__ void tf2x32(uint32_t ka, uint32_t kb,
                                       uint32_t x0, uint32_t x1,
                                       uint32_t& o0, uint32_t& o1) {
  const uint32_t kc = ka ^ kb ^ 0x1BD11BDAu;
  x0 += ka; x1 += kb;
#define TF_R4(r0, r1, r2, r3)                          \
  x0 += x1; x1 = rotl32(x1, r0); x1 ^= x0;             \
  x0 += x1; x1 = rotl32(x1, r1); x1 ^= x0;             \
  x0 += x1; x1 = rotl32(x1, r2); x1 ^= x0;             \
  x0 += x1; x1 = rotl32(x1, r3); x1 ^= x0;
  TF_R4(13, 15, 26, 6)  x0 += kb; x1 += kc + 1u;
  TF_R4(17, 29, 16, 24) x0 += kc; x1 += ka + 2u;
  TF_R4(13, 15, 26, 6)  x0 += ka; x1 += kb + 3u;
  TF_R4(17, 29, 16, 24) x0 += kb; x1 += kc + 4u;
  TF_R4(13, 15, 26, 6)  x0 += kc; x1 += ka + 5u;
#undef TF_R4
  o0 = x0; o1 = x1;
}

// (hi, lo) bits of jax.random.randint(key, (), 0, span): span-independent.
__device__ __forceinline__ void randbits(uint32_t ka, uint32_t kb,
                                         uint32_t& hi, uint32_t& lo) {
  uint32_t s0a, s0b, s1a, s1b, h0, h1;
  tf2x32(ka, kb, 0u, 0u, s0a, s0b);   // split(key)[0]
  tf2x32(ka, kb, 0u, 1u, s1a, s1b);   // split(key)[1]
  tf2x32(s0a, s0b, 0u, 0u, h0, h1);
  hi = h0 ^ h1;
  tf2x32(s1a, s1b, 0u, 0u, h0, h1);
  lo = h0 ^ h1;
}

__device__ __forceinline__ uint32_t r_generic(uint32_t hi, uint32_t lo,
                                              uint32_t span) {
  uint32_t mult = 65536u % span;
  mult = (mult * mult) % span;
  return ((hi % span) * mult + (lo % span)) % span;
}

// pick code: r3 (span=3 result) in bits 0..1, r2 (span=2 result) in bit 2.
__device__ __forceinline__ uint32_t pick_code(uint32_t hi, uint32_t lo) {
  return ((hi % 3u + lo % 3u) % 3u) | ((lo & 1u) << 2);
}

constexpr int WPB = 16;       // walks per block (2 per wave)
constexpr int CH = 64;        // cached chain length (covers seq_len 63)
constexpr int NMAX = 20000;   // LDS-table capacity (rows)
constexpr int VISW = 625;     // bitmap words per walk = ceil(NMAX/32)
constexpr int THREADS = 512;  // 8 waves

__global__ __launch_bounds__(512) void walk_kernel(
    const float* __restrict__ xyz, const int* __restrict__ nbrs,
    const int* __restrict__ centers, const int* __restrict__ n_faces_p,
    const int* __restrict__ seq_len_p, float* __restrict__ out,
    int s0, int num_walks, int Lp1) {
  // 80,000 + 40,000 + 40,000 + 2,176 + 192 = 162,368 B
  __shared__ uint32_t nb01L[NMAX];          // n0 | n1<<16
  __shared__ uint16_t nb2L[NMAX];           // n2
  __shared__ __align__(16) uint32_t visL[WPB * VISW];  // bitmaps; scratch
  __shared__ uint16_t seqL[WPB][CH + 4];    // +4 pad
  __shared__ float cenL[WPB][3];            // center xyz per walk

  const int tid = threadIdx.x;
  const int wv = tid >> 6, lane = tid & 63;
  const int w0 = blockIdx.x * WPB;
  if (w0 >= num_walks) return;               // block-uniform

  const int N = *n_faces_p;
  const int L = *seq_len_p;
  const int B = s0 / (3 * N);
  const int G = num_walks / B;
  const bool lds_ok = (N <= NMAX) && (G % WPB == 0) && (L < CH);
  const int bb0 = w0 / G;                    // all 16 walks share a batch

  // ---- Phase A: wave 0 lanes<16 = key carry chains -> visL[0..2047];
  //      waves 1..7 = table staging (lds_ok only). ------------------------
  if (wv == 0) {
    if (lane < WPB && (w0 + lane) < num_walks) {
      uint32_t ka, kb;
      tf2x32(0u, 42u, 0u, (uint32_t)(w0 + lane), ka, kb);  // k_0
      visL[(lane * CH + 0) * 2 + 0] = ka;
      visL[(lane * CH + 0) * 2 + 1] = kb;
#pragma clang loop unroll(disable)
      for (int c2 = 1; c2 < CH; ++c2) {
        tf2x32(ka, kb, 0u, 0u, ka, kb);
        visL[(lane * CH + c2) * 2 + 0] = ka;
        visL[(lane * CH + c2) * 2 + 1] = kb;
      }
    }
  } else if (lds_ok) {
    const int* __restrict__ nbT = nbrs + (size_t)bb0 * N * 3;
    for (int r = tid - 64; r < N; r += (THREADS - 64)) {
      const int3 v = *reinterpret_cast<const int3*>(nbT + 3 * (size_t)r);
      nb01L[r] = (uint32_t)v.x | ((uint32_t)v.y << 16);
      nb2L[r]  = (uint16_t)v.z;
    }
  }
  __syncthreads();   // barrier 1: keys + table staged

  if (lds_ok) {
    const float* __restrict__ xb = xyz + (size_t)bb0 * N * 3;
    // ---- Phase B: per-step codes, (walk,step) pairs over all threads ----
    uint8_t* const codesB = reinterpret_cast<uint8_t*>(&visL[2048]);
#pragma unroll
    for (int p = 0; p < (WPB * CH) / THREADS; ++p) {   // 2 pairs/thread
      const int pair = tid + THREADS * p;
      const int wk = pair >> 6, st = pair & 63;
      if ((w0 + wk) < num_walks) {
        const uint32_t ka = visL[(wk * CH + st) * 2 + 0];
        const uint32_t kb = visL[(wk * CH + st) * 2 + 1];
        uint32_t k1a, k1b, hi, lo;
        tf2x32(ka, kb, 0u, 1u, k1a, k1b);   // k1 = split(k,4)[1]
        randbits(k1a, k1b, hi, lo);
        codesB[wk * CH + st] = (uint8_t)pick_code(hi, lo);
      }
    }
    // centers -> cenL (16 threads; overlaps codes work of others)
    if (tid < WPB && (w0 + tid) < num_walks) {
      const int f0t = centers[w0 + tid];
      cenL[tid][0] = xb[3 * (size_t)f0t + 0];
      cenL[tid][1] = xb[3 * (size_t)f0t + 1];
      cenL[tid][2] = xb[3 * (size_t)f0t + 2];
    }
    __syncthreads();   // barrier 2: codes + centers ready

    // ---- Phase C: walker lanes (0 and 32 of each wave) pack codes -------
    const int kw = 2 * wv + (lane >> 5);     // walk slot for this half
    const int w = w0 + kw;
    const bool walker = ((lane & 31) == 0) && (w < num_walks);
    uint32_t cw[7] = {0, 0, 0, 0, 0, 0, 0};
    uint32_t k0a = 0, k0b = 0;
    if (walker) {
      tf2x32(0u, 42u, 0u, (uint32_t)w, k0a, k0b);   // cheap k_0 recompute
      const uint32_t* cwd = &visL[2048 + kw * (CH / 4)];
#pragma unroll
      for (int t = 0; t < CH / 4; ++t) {
        const uint32_t wd = cwd[t];
#pragma unroll
        for (int b = 0; b < 4; ++b) {
          const int s = 4 * t + b;               // compile-time
          const uint32_t c3 = (wd >> (8 * b)) & 7u;
          cw[s / 10] |= c3 << (3 * (s % 10));    // constant indices only
        }
      }
    }
    __syncthreads();   // barrier 3: scratch reads done
    // ---- Phase D: zero bitmaps (b128; visL is 16B-aligned, 2500 uint4) --
    {
      uint4* const v4 = reinterpret_cast<uint4*>(visL);
      const uint4 z = make_uint4(0u, 0u, 0u, 0u);
      for (int j = tid; j < (WPB * VISW) / 4; j += THREADS) v4[j] = z;
    }
    __syncthreads();   // barrier 4: bitmaps ready

    // =================== 8 waves x 2 lane-local walks ====================
    const int f0 = walker ? centers[w] : 0;
    uint32_t* __restrict__ visW = visL + (walker ? kw : 0) * VISW;

    if (walker) {
      visW[(unsigned)f0 >> 5] = 1u << (f0 & 31);
      seqL[kw][0] = (uint16_t)f0;
    }

    // candidate state + 1-iter prefetch of rows and vis words
    const uint32_t p0 = nb01L[f0];
    int n0 = (int)(p0 & 0xffffu), n1 = (int)(p0 >> 16), n2 = (int)nb2L[f0];
    uint32_t pA01 = nb01L[n0], pB01 = nb01L[n1], pC01 = nb01L[n2];
    uint32_t pA2 = nb2L[n0], pB2 = nb2L[n1], pC2 = nb2L[n2];
    uint32_t wd0 = visW[(unsigned)n0 >> 5];
    uint32_t wd1 = visW[(unsigned)n1 >> 5];
    uint32_t wd2 = visW[(unsigned)n2 >> 5];

    int extc = 0; uint32_t extka = k0a, extkb = k0b;   // extka = k_extc
    const uint32_t wknot = walker ? 0u : 1u;  // forces __any mask off junk

    // ---------------- pristine fast loop: i == c+1, bs == 1 --------------
    int c = 0;
    for (; c < L; ++c) {
      const uint32_t u0 = ((wd0 >> (n0 & 31)) & 1u) ^ 1u;
      const uint32_t u1 = ((wd1 >> (n1 & 31)) & 1u) ^ 1u;
      const uint32_t u2 = ((wd2 >> (n2 & 31)) & 1u) ^ 1u;
      const uint32_t cnt = u0 + u1 + u2;
      if (__builtin_expect(__any((cnt | wknot) == 0u), 0)) break;  // -> slow

      // code from packed registers (ladder off the critical chain)
      const int wi = c / 10;
      const int sh = 3 * (c - wi * 10);
      uint32_t cwv = cw[0];
      cwv = (wi == 1) ? cw[1] : cwv;  cwv = (wi == 2) ? cw[2] : cwv;
      cwv = (wi == 3) ? cw[3] : cwv;  cwv = (wi == 4) ? cw[4] : cwv;
      cwv = (wi == 5) ? cw[5] : cwv;  cwv = (wi == 6) ? cw[6] : cwv;
      const uint32_t code = (cwv >> sh) & 7u;

      const uint32_t r3 = code & 3u, r2 = (code >> 2) & 1u;
      const uint32_t tgt = (cnt == 3 ? r3 : (cnt == 2 ? r2 : 0)) + 1;
      const int sel = (u0 == tgt) ? 0 : ((u0 + u1 == tgt) ? 1 : 2);
      const int to_add = (sel == 0) ? n0 : ((sel == 1) ? n1 : n2);
      const uint32_t wsel = (sel == 0) ? wd0 : ((sel == 1) ? wd1 : wd2);

      if (walker) {   // loop-invariant 2-lane mask; 2 stores, in-order DS
        visW[(unsigned)to_add >> 5] = wsel | (1u << (to_add & 31));
        seqL[kw][c + 1] = (uint16_t)to_add;
      }

      if (sel == 0)      { n0 = (int)(pA01 & 0xffffu); n1 = (int)(pA01 >> 16); n2 = (int)pA2; }
      else if (sel == 1) { n0 = (int)(pB01 & 0xffffu); n1 = (int)(pB01 >> 16); n2 = (int)pB2; }
      else               { n0 = (int)(pC01 & 0xffffu); n1 = (int)(pC01 >> 16); n2 = (int)pC2; }

      // prefetch next-iter rows + vis words (after the bit write: in-order)
      pA01 = nb01L[n0]; pA2 = nb2L[n0];
      pB01 = nb01L[n1]; pB2 = nb2L[n1];
      pC01 = nb01L[n2]; pC2 = nb2L[n2];
      wd0 = visW[(unsigned)n0 >> 5];
      wd1 = visW[(unsigned)n1 >> 5];
      wd2 = visW[(unsigned)n2 >> 5];
    }

    // ---------------- general slow loop (R12 body, verified) -------------
    if (__builtin_expect(c < L, 0)) {
      int i = walker ? (c + 1) : (L + 1);
      int bs = 1;
      for (;; ++c) {
        if (!__any(i <= L)) break;
        const bool act = (i <= L);

        const uint32_t u0 = ((wd0 >> (n0 & 31)) & 1u) ^ 1u;
        const uint32_t u1 = ((wd1 >> (n1 & 31)) & 1u) ^ 1u;
        const uint32_t u2 = ((wd2 >> (n2 & 31)) & 1u) ^ 1u;
        const uint32_t cnt = u0 + u1 + u2;

        uint32_t code;
        if (__builtin_expect(c < CH, 1)) {
          const int wi = c / 10;                    // uniform
          const int sh = 3 * (c - wi * 10);
          uint32_t cwv = cw[0];
          cwv = (wi == 1) ? cw[1] : cwv;  cwv = (wi == 2) ? cw[2] : cwv;
          cwv = (wi == 3) ? cw[3] : cwv;  cwv = (wi == 4) ? cw[4] : cwv;
          cwv = (wi == 5) ? cw[5] : cwv;  cwv = (wi == 6) ? cw[6] : cwv;
          code = (cwv >> sh) & 7u;
        } else {
          // live tree beyond cached steps (only after backtracks; uniform c)
          while (extc < c) { tf2x32(extka, extkb, 0u, 0u, extka, extkb); ++extc; }
          uint32_t k1a, k1b, hi, lo;
          tf2x32(extka, extkb, 0u, 1u, k1a, k1b);
          randbits(k1a, k1b, hi, lo);
          code = pick_code(hi, lo);
        }

        const bool need = act && (cnt == 0u);
        if (__builtin_expect(__any(need), 0)) {
          // ---- rare path (lane-local backtrack; bit-exact) ----
          while (extc < c) { tf2x32(extka, extkb, 0u, 0u, extka, extkb); ++extc; }
          const uint32_t kia = extka, kib = extkb;   // = k_c
          bool found = false; int ta = 0; int bsc = bs;
          if (need) {
            uint32_t kka, kkb;
            tf2x32(kia, kib, 0u, 2u, kka, kkb);      // k2
            while (!found && i > bsc) {
              uint32_t ca, cb, kpa, kpb;
              tf2x32(kka, kkb, 0u, 0u, ca, cb);
              tf2x32(kka, kkb, 0u, 1u, kpa, kpb);
              const int back = (int)seqL[kw][i - bsc - 1];
              const uint32_t pm = nb01L[back];
              const int m0 = (int)(pm & 0xffffu), m1 = (int)(pm >> 16);
              const int m2 = (int)nb2L[back];
              const uint32_t e0 = ((visW[(unsigned)m0 >> 5] >> (m0 & 31)) & 1u) ^ 1u;
              const uint32_t e1 = ((visW[(unsigned)m1 >> 5] >> (m1 & 31)) & 1u) ^ 1u;
              const uint32_t e2 = ((visW[(unsigned)m2 >> 5] >> (m2 & 31)) & 1u) ^ 1u;
              const uint32_t bc = e0 + e1 + e2;
              if (bc > 0) {
                uint32_t bhi, blo;
                randbits(kpa, kpb, bhi, blo);
                const uint32_t bcode = pick_code(bhi, blo);
                const uint32_t br3 = bcode & 3u, br2 = (bcode >> 2) & 1u;
                const uint32_t t2v = (bc == 3 ? br3 : (bc == 2 ? br2 : 0)) + 1;
                ta = (e0 == t2v) ? m0 : ((e0 + e1 == t2v) ? m1 : m2);
                found = true;
              } else {
                bsc += 2;
              }
              kka = ca; kkb = cb;
            }
          }
          int rnd = 0;
          if (need && !found) {
            uint32_t k3a, k3b, rhi, rlo;
            tf2x32(kia, kib, 0u, 3u, k3a, k3b);      // k3
            randbits(k3a, k3b, rhi, rlo);
            rnd = (int)r_generic(rhi, rlo, (uint32_t)N);
          }
          // common-path candidate for act && !need lanes
          const uint32_t r3 = code & 3u, r2 = (code >> 2) & 1u;
          const uint32_t tgt = (cnt == 3 ? r3 : (cnt == 2 ? r2 : 0)) + 1;
          const int selc = (u0 == tgt) ? 0 : ((u0 + u1 == tgt) ? 1 : 2);
          const int to_add_c = (selc == 0) ? n0 : ((selc == 1) ? n1 : n2);
          const uint32_t wselc = (selc == 0) ? wd0 : ((selc == 1) ? wd1 : wd2);

          const bool hit = need && found;
          const int to_add = need ? (found ? ta : rnd) : to_add_c;

          if (act) {
            uint32_t wdf = need ? visW[(unsigned)to_add >> 5] : wselc;
            visW[(unsigned)to_add >> 5] = wdf | (1u << (to_add & 31));
            if (hit) {
              const int i_new = i - bsc;
              for (int j = i_new; j < i; ++j) seqL[kw][j] = (uint16_t)to_add;
              bs = bsc; i = i_new + 1;
            } else {
              seqL[kw][i] = (uint16_t)to_add;
              bs = 1; ++i;
            }
          }
          // next candidates: dependent row read (rare)
          const int rn = act ? to_add : 0;
          const uint32_t pr = nb01L[rn];
          const uint32_t pr2 = nb2L[rn];
          if (act) {
            n0 = (int)(pr & 0xffffu); n1 = (int)(pr >> 16); n2 = (int)pr2;
          }
        } else {
          // ---- common path: branch-lean, fully lane-local ----
          const uint32_t r3 = code & 3u, r2 = (code >> 2) & 1u;
          const uint32_t tgt = (cnt == 3 ? r3 : (cnt == 2 ? r2 : 0)) + 1;
          const int sel = (u0 == tgt) ? 0 : ((u0 + u1 == tgt) ? 1 : 2);
          const int to_add = (sel == 0) ? n0 : ((sel == 1) ? n1 : n2);
          const uint32_t wsel = (sel == 0) ? wd0 : ((sel == 1) ? wd1 : wd2);
          if (act) {
            visW[(unsigned)to_add >> 5] = wsel | (1u << (to_add & 31));
            seqL[kw][i] = (uint16_t)to_add;
            bs = 1; ++i;
            if (sel == 0)      { n0 = (int)(pA01 & 0xffffu); n1 = (int)(pA01 >> 16); n2 = (int)pA2; }
            else if (sel == 1) { n0 = (int)(pB01 & 0xffffu); n1 = (int)(pB01 >> 16); n2 = (int)pB2; }
            else               { n0 = (int)(pC01 & 0xffffu); n1 = (int)(pC01 >> 16); n2 = (int)pC2; }
          }
        }
        // prefetch rows + vis words for next iteration
        pA01 = nb01L[n0]; pA2 = nb2L[n0];
        pB01 = nb01L[n1]; pB2 = nb2L[n1];
        pC01 = nb01L[n2]; pC2 = nb2L[n2];
        wd0 = visW[(unsigned)n0 >> 5];
        wd1 = visW[(unsigned)n1 >> 5];
        wd2 = visW[(unsigned)n2 >> 5];
      }
    }

    __syncthreads();   // barrier 5: all walks complete, seqL final

    // ---- Epilogue: block-wide gather-recenter from seqL -----------------
    const int items = WPB * Lp1;
    for (int idx = tid; idx < items; idx += THREADS) {
      const int wl = idx / Lp1;
      const int p = idx - wl * Lp1;
      const int ww = w0 + wl;
      if (ww < num_walks) {
        const int node = (int)seqL[wl][p];
        const float* xr = xb + 3 * (size_t)node;
        float3 v;
        v.x = xr[0] - cenL[wl][0];
        v.y = xr[1] - cenL[wl][1];
        v.z = xr[2] - cenL[wl][2];
        *reinterpret_cast<float3*>(out + ((size_t)ww * Lp1 + p) * 3) = v;
      }
    }
  } else {
    // ============ global-chase fallback (verified R5/R8/R10 logic) =======
    // 8 waves x 2 sequential full-wave walks; keys intact in visL scratch.
    for (int sub = 0; sub < 2; ++sub) {
      const int w = w0 + 2 * wv + sub;
      if (w >= num_walks) continue;          // wave-uniform
      const int bb = w / G;
      const int* __restrict__ nbG = nbrs + (size_t)bb * N * 3;
      const float* __restrict__ xb = xyz + (size_t)bb * N * 3;
      const int f0 = centers[w];
      const uint32_t mka = visL[((2 * wv + sub) * CH + lane) * 2 + 0];
      const uint32_t mkb = visL[((2 * wv + sub) * CH + lane) * 2 + 1];
      uint32_t mycode;
      {
        uint32_t k1a, k1b, hi, lo;
        tf2x32(mka, mkb, 0u, 1u, k1a, k1b);
        randbits(k1a, k1b, hi, lo);
        mycode = pick_code(hi, lo);
      }
      uint32_t extka = 0, extkb = 0;
      int extc = -1;
      auto get_key = [&](int idxk, uint32_t& ra, uint32_t& rb) {
        if (idxk < CH) {
          ra = (uint32_t)__shfl((int)mka, idxk);
          rb = (uint32_t)__shfl((int)mkb, idxk);
        } else {
          if (extc < 0) {
            extka = (uint32_t)__shfl((int)mka, CH - 1);
            extkb = (uint32_t)__shfl((int)mkb, CH - 1);
            extc = CH - 1;
          }
          while (extc < idxk) { tf2x32(extka, extkb, 0u, 0u, extka, extkb); ++extc; }
          ra = extka; rb = extkb;
        }
      };

      int seqr = (lane == 0) ? f0 : -1;
      uint32_t code_next = (uint32_t)__shfl((int)mycode, 0);
      int i = 1, bs = 1, c = 0;
      int hist  = (lane == 0) ? f0 : -1;
      int hist2 = -1;
      int3 row = *reinterpret_cast<const int3*>(nbG + 3 * (size_t)f0);
      while (i <= L) {
        const int idx = c; ++c;
        const bool deep = (idx >= CH);
        const uint32_t codeP = code_next;
        code_next = (uint32_t)__shfl((int)mycode, (c < CH) ? c : 0);

        const int n0 = row.x, n1 = row.y, n2 = row.z;
        int v0 = __any(hist == n0), v1 = __any(hist == n1), v2 = __any(hist == n2);
        if (deep) {
          v0 |= __any(hist2 == n0); v1 |= __any(hist2 == n1); v2 |= __any(hist2 == n2);
        }
        const int u0 = 1 - v0, u1 = 1 - v1, u2 = 1 - v2;
        const int cnt = u0 + u1 + u2;

        int to_add;
        bool hit = false;
        int bsf = bs;
        if (cnt > 0) {
          uint32_t code = codeP;
          if (deep) {
            uint32_t ia, ib, k1a, k1b, hi, lo;
            get_key(idx, ia, ib);
            tf2x32(ia, ib, 0u, 1u, k1a, k1b);
            randbits(k1a, k1b, hi, lo);
            code = pick_code(hi, lo);
          }
          const int r3 = (int)(code & 3u), r2 = (int)((code >> 2) & 1u);
          const int target = (cnt == 3 ? r3 : (cnt == 2 ? r2 : 0)) + 1;
          to_add = (u0 == target) ? n0 : ((u0 + u1 == target) ? n1 : n2);
        } else {
          uint32_t kia, kib;
          get_key(idx, kia, kib);
          uint32_t kka, kkb;
          tf2x32(kia, kib, 0u, 2u, kka, kkb);
          bool found = false;
          int ta = 0, bsc = bs;
          while (!found && i > bsc) {
            uint32_t ca, cb, kpa, kpb;
            tf2x32(kka, kkb, 0u, 0u, ca, cb);
            tf2x32(kka, kkb, 0u, 1u, kpa, kpb);
            const int back = __shfl(seqr, i - bsc - 1);
            const int3 br = *reinterpret_cast<const int3*>(nbG + 3 * (size_t)back);
            int w0m = __any(hist == br.x), w1m = __any(hist == br.y), w2m = __any(hist == br.z);
            if (deep) {
              w0m |= __any(hist2 == br.x); w1m |= __any(hist2 == br.y); w2m |= __any(hist2 == br.z);
            }
            const int e0 = 1 - w0m, e1 = 1 - w1m, e2 = 1 - w2m;
            const int bc = e0 + e1 + e2;
            if (bc > 0) {
              uint32_t bhi, blo;
              randbits(kpa, kpb, bhi, blo);
              const uint32_t bcode = pick_code(bhi, blo);
              const int r3 = (int)(bcode & 3u), r2 = (int)((bcode >> 2) & 1u);
              const int t2v = (bc == 3 ? r3 : (bc == 2 ? r2 : 0)) + 1;
              ta = (e0 == t2v) ? br.x : ((e0 + e1 == t2v) ? br.y : br.z);
              found = true;
            } else {
              bsc += 2;
            }
            kka = ca; kkb = cb;
          }
          if (found) {
            to_add = ta; hit = true; bsf = bsc;
          } else {
            uint32_t k3a, k3b, rhi, rlo;
            tf2x32(kia, kib, 0u, 3u, k3a, k3b);
            randbits(k3a, k3b, rhi, rlo);
            to_add = (int)r_generic(rhi, rlo, (uint32_t)N);
          }
        }

        int i_new, up;
        if (hit) { i_new = i - bsf; bs = bsf; up = i - 1; }
        else     { i_new = i;       bs = 1;   up = i; }
        seqr = (lane >= i_new && lane <= up) ? to_add : seqr;

        const int slot = idx + 1;
        if (slot < CH)          hist  = (lane == slot)      ? to_add : hist;
        else if (slot < 2 * CH) hist2 = (lane == slot - CH) ? to_add : hist2;

        i = i_new + 1;
        row = *reinterpret_cast<const int3*>(nbG + 3 * (size_t)to_add);
      }

      const float cx = xb[3 * (size_t)f0 + 0];
      const float cy = xb[3 * (size_t)f0 + 1];
      const float cz = xb[3 * (size_t)f0 + 2];
      if (lane < Lp1) {
        const int node = seqr;
        float3 v;
        v.x = xb[3 * (size_t)node + 0] - cx;
        v.y = xb[3 * (size_t)node + 1] - cy;
        v.z = xb[3 * (size_t)node + 2] - cz;
        *reinterpret_cast<float3*>(out + ((size_t)w * Lp1 + lane) * 3) = v;
      }
    }
  }
}

}  // namespace

extern "C" void kernel_launch(void* const* d_in, const int* in_sizes, int n_in,
                              void* d_out, int out_size, void* d_ws, size_t ws_size,
                              hipStream_t stream) {
  const float* xyz     = (const float*)d_in[0];
  const int*   nbrs    = (const int*)d_in[1];
  const int*   centers = (const int*)d_in[2];
  const int*   n_faces = (const int*)d_in[3];
  const int*   seq_len = (const int*)d_in[4];
  float* out = (float*)d_out;

  const int s0 = in_sizes[0];                  // B*N*3
  const int num_walks = in_sizes[2];           // B*G
  const int Lp1 = out_size / (3 * num_walks);  // seq_len+1

  const int blocks = (num_walks + WPB - 1) / WPB;
  walk_kernel<<<blocks, THREADS, 0, stream>>>(
      xyz, nbrs, centers, n_faces, seq_len, out, s0, num_walks, Lp1);
}

// Round 6
// 90.376 us; speedup vs baseline: 1.2282x; 1.0800x over previous
//
#include <hip/hip_runtime.h>
#include <stdint.h>
#include <stddef.h>

// MambaMesh random-walk + gather-recenter.  R14: unrolled branchless fast63.
// PRNG (bit-exact vs JAX partitionable Threefry, verified R1-R13, absmax 0.0):
//   split(key,n)[j]        = threefry2x32(key; 0, j)   (both output words)
//   random_bits(key,32,()) = xor-fold of threefry2x32(key; 0, 0)
// R13 post-mortem: fast loop helped (48->40.6us) but walk phase still
// ~28us =~1050cyc/iter vs ~250cyc data chain + ~510cyc/round DS pipe.
// Remaining per-iter machinery: __any exit (VALU->vcc->SALU->branch round
// trip, splits scheduling regions), c/10 div + 6-cndmask code ladder, loop
// control. R14: L==63 specialization -> FULLY UNROLLED 63-step straight
// line, zero branches: code index compile-time (ladder folds to one reg),
// stuck-ness -> sticky register bit, checked ONCE at end. Stuck walks
// (P~3e-8/step) REPLAY from scratch via the verified R12 general loop
// (re-zero own bitmap) -> bit-exact for all inputs. L!=63 -> general loop.
//   block = 512 thr (8 waves), walker lanes 0/32, 16 walks/block, 256 blocks.
//   LDS: table 120,000 + bitmaps 40,000 + seq 2,176 + centers 192
//        = 162,368 B. Keys scratch visL[0..2047], codes visL[2048..2303].

namespace {

__device__ __forceinline__ uint32_t rotl32(uint32_t x, int r) {
  return (x << r) | (x >> (32 - r));
}

// Threefry-2x32, 20 rounds — exactly JAX's threefry2x32_p.
__device__ __forceinline__ void tf2x32(uint32_t ka, uint32_t kb,
                                       uint32_t x0, uint32_t x1,
                                       uint32_t& o0, uint32_t& o1) {
  const uint32_t kc = ka ^ kb ^ 0x1BD11BDAu;
  x0 += ka; x1 += kb;
#define TF_R4(r0, r1, r2, r3)                          \
  x0 += x1; x1 = rotl32(x1, r0); x1 ^= x0;             \
  x0 += x1; x1 = rotl32(x1, r1); x1 ^= x0;             \
  x0 += x1; x1 = rotl32(x1, r2); x1 ^= x0;             \
  x0 += x1; x1 = rotl32(x1, r3); x1 ^= x0;
  TF_R4(13, 15, 26, 6)  x0 += kb; x1 += kc + 1u;
  TF_R4(17, 29, 16, 24) x0 += kc; x1 += ka + 2u;
  TF_R4(13, 15, 26, 6)  x0 += ka; x1 += kb + 3u;
  TF_R4(17, 29, 16, 24) x0 += kb; x1 += kc + 4u;
  TF_R4(13, 15, 26, 6)  x0 += kc; x1 += ka + 5u;
#undef TF_R4
  o0 = x0; o1 = x1;
}

// (hi, lo) bits of jax.random.randint(key, (), 0, span): span-independent.
__device__ __forceinline__ void randbits(uint32_t ka, uint32_t kb,
                                         uint32_t& hi, uint32_t& lo) {
  uint32_t s0a, s0b, s1a, s1b, h0, h1;
  tf2x32(ka, kb, 0u, 0u, s0a, s0b);   // split(key)[0]
  tf2x32(ka, kb, 0u, 1u, s1a, s1b);   // split(key)[1]
  tf2x32(s0a, s0b, 0u, 0u, h0, h1);
  hi = h0 ^ h1;
  tf2x32(s1a, s1b, 0u, 0u, h0, h1);
  lo = h0 ^ h1;
}

__device__ __forceinline__ uint32_t r_generic(uint32_t hi, uint32_t lo,
                                              uint32_t span) {
  uint32_t mult = 65536u % span;
  mult = (mult * mult) % span;
  return ((hi % span) * mult + (lo % span)) % span;
}

// pick code: r3 (span=3 result) in bits 0..1, r2 (span=2 result) in bit 2.
__device__ __forceinline__ uint32_t pick_code(uint32_t hi, uint32_t lo) {
  return ((hi % 3u + lo % 3u) % 3u) | ((lo & 1u) << 2);
}

constexpr int WPB = 16;       // walks per block (2 per wave)
constexpr int CH = 64;        // cached chain length (covers seq_len 63)
constexpr int NMAX = 20000;   // LDS-table capacity (rows)
constexpr int VISW = 625;     // bitmap words per walk = ceil(NMAX/32)
constexpr int THREADS = 512;  // 8 waves

__global__ __launch_bounds__(512) void walk_kernel(
    const float* __restrict__ xyz, const int* __restrict__ nbrs,
    const int* __restrict__ centers, const int* __restrict__ n_faces_p,
    const int* __restrict__ seq_len_p, float* __restrict__ out,
    int s0, int num_walks, int Lp1) {
  // 80,000 + 40,000 + 40,000 + 2,176 + 192 = 162,368 B
  __shared__ uint32_t nb01L[NMAX];          // n0 | n1<<16
  __shared__ uint16_t nb2L[NMAX];           // n2
  __shared__ __align__(16) uint32_t visL[WPB * VISW];  // bitmaps; scratch
  __shared__ uint16_t seqL[WPB][CH + 4];    // +4 pad
  __shared__ float cenL[WPB][3];            // center xyz per walk

  const int tid = threadIdx.x;
  const int wv = tid >> 6, lane = tid & 63;
  const int w0 = blockIdx.x * WPB;
  if (w0 >= num_walks) return;               // block-uniform

  const int N = *n_faces_p;
  const int L = *seq_len_p;
  const int B = s0 / (3 * N);
  const int G = num_walks / B;
  const bool lds_ok = (N <= NMAX) && (G % WPB == 0) && (L < CH);
  const int bb0 = w0 / G;                    // all 16 walks share a batch

  // ---- Phase A: wave 0 lanes<16 = key carry chains -> visL[0..2047];
  //      waves 1..7 = table staging (lds_ok only). ------------------------
  if (wv == 0) {
    if (lane < WPB && (w0 + lane) < num_walks) {
      uint32_t ka, kb;
      tf2x32(0u, 42u, 0u, (uint32_t)(w0 + lane), ka, kb);  // k_0
      visL[(lane * CH + 0) * 2 + 0] = ka;
      visL[(lane * CH + 0) * 2 + 1] = kb;
#pragma clang loop unroll(disable)
      for (int c2 = 1; c2 < CH; ++c2) {
        tf2x32(ka, kb, 0u, 0u, ka, kb);
        visL[(lane * CH + c2) * 2 + 0] = ka;
        visL[(lane * CH + c2) * 2 + 1] = kb;
      }
    }
  } else if (lds_ok) {
    const int* __restrict__ nbT = nbrs + (size_t)bb0 * N * 3;
    for (int r = tid - 64; r < N; r += (THREADS - 64)) {
      const int3 v = *reinterpret_cast<const int3*>(nbT + 3 * (size_t)r);
      nb01L[r] = (uint32_t)v.x | ((uint32_t)v.y << 16);
      nb2L[r]  = (uint16_t)v.z;
    }
  }
  __syncthreads();   // barrier 1: keys + table staged

  if (lds_ok) {
    const float* __restrict__ xb = xyz + (size_t)bb0 * N * 3;
    // ---- Phase B: per-step codes, (walk,step) pairs over all threads ----
    uint8_t* const codesB = reinterpret_cast<uint8_t*>(&visL[2048]);
#pragma unroll
    for (int p = 0; p < (WPB * CH) / THREADS; ++p) {   // 2 pairs/thread
      const int pair = tid + THREADS * p;
      const int wk = pair >> 6, st = pair & 63;
      if ((w0 + wk) < num_walks) {
        const uint32_t ka = visL[(wk * CH + st) * 2 + 0];
        const uint32_t kb = visL[(wk * CH + st) * 2 + 1];
        uint32_t k1a, k1b, hi, lo;
        tf2x32(ka, kb, 0u, 1u, k1a, k1b);   // k1 = split(k,4)[1]
        randbits(k1a, k1b, hi, lo);
        codesB[wk * CH + st] = (uint8_t)pick_code(hi, lo);
      }
    }
    // centers -> cenL (16 threads; overlaps codes work of others)
    if (tid < WPB && (w0 + tid) < num_walks) {
      const int f0t = centers[w0 + tid];
      cenL[tid][0] = xb[3 * (size_t)f0t + 0];
      cenL[tid][1] = xb[3 * (size_t)f0t + 1];
      cenL[tid][2] = xb[3 * (size_t)f0t + 2];
    }
    __syncthreads();   // barrier 2: codes + centers ready

    // ---- Phase C: walker lanes (0 and 32 of each wave) pack codes -------
    const int kw = 2 * wv + (lane >> 5);     // walk slot for this half
    const int w = w0 + kw;
    const bool walker = ((lane & 31) == 0) && (w < num_walks);
    uint32_t cw[7] = {0, 0, 0, 0, 0, 0, 0};
    uint32_t k0a = 0, k0b = 0;
    if (walker) {
      tf2x32(0u, 42u, 0u, (uint32_t)w, k0a, k0b);   // cheap k_0 recompute
      const uint32_t* cwd = &visL[2048 + kw * (CH / 4)];
#pragma unroll
      for (int t = 0; t < CH / 4; ++t) {
        const uint32_t wd = cwd[t];
#pragma unroll
        for (int b = 0; b < 4; ++b) {
          const int s = 4 * t + b;               // compile-time
          const uint32_t c3 = (wd >> (8 * b)) & 7u;
          cw[s / 10] |= c3 << (3 * (s % 10));    // constant indices only
        }
      }
    }
    __syncthreads();   // barrier 3: scratch reads done
    // ---- Phase D: zero bitmaps (b128; visL is 16B-aligned, 2500 uint4) --
    {
      uint4* const v4 = reinterpret_cast<uint4*>(visL);
      const uint4 z = make_uint4(0u, 0u, 0u, 0u);
      for (int j = tid; j < (WPB * VISW) / 4; j += THREADS) v4[j] = z;
    }
    __syncthreads();   // barrier 4: bitmaps ready

    // =================== 8 waves x 2 lane-local walks ====================
    const int f0 = walker ? centers[w] : 0;
    uint32_t* __restrict__ visW = visL + (walker ? kw : 0) * VISW;

    if (walker) {
      visW[(unsigned)f0 >> 5] = 1u << (f0 & 31);
      seqL[kw][0] = (uint16_t)f0;
    }

    // candidate state + 1-iter prefetch of rows and vis words
    const uint32_t p0 = nb01L[f0];
    int n0 = (int)(p0 & 0xffffu), n1 = (int)(p0 >> 16), n2 = (int)nb2L[f0];
    uint32_t pA01 = nb01L[n0], pB01 = nb01L[n1], pC01 = nb01L[n2];
    uint32_t pA2 = nb2L[n0], pB2 = nb2L[n1], pC2 = nb2L[n2];
    uint32_t wd0 = visW[(unsigned)n0 >> 5];
    uint32_t wd1 = visW[(unsigned)n1 >> 5];
    uint32_t wd2 = visW[(unsigned)n2 >> 5];

    int extc = 0; uint32_t extka = k0a, extkb = k0b;   // extka = k_extc
    int c = 0, bs = 1;
    int i = L + 1;              // default: inactive in general loop
    bool do_general = true;

    if (L == 63) {
      // ------- fully unrolled branchless fast path (63 steps) ------------
      uint32_t sticky = 0u;
#pragma clang loop unroll(full)
      for (int cc = 0; cc < 63; ++cc) {
        const uint32_t u0 = ((wd0 >> (n0 & 31)) & 1u) ^ 1u;
        const uint32_t u1 = ((wd1 >> (n1 & 31)) & 1u) ^ 1u;
        const uint32_t u2 = ((wd2 >> (n2 & 31)) & 1u) ^ 1u;
        const uint32_t cnt = u0 + u1 + u2;
        sticky |= (cnt == 0u) ? 1u : 0u;           // no branch; junk-safe
        // cc compile-time -> single register read, no ladder/div
        const uint32_t code = (cw[cc / 10] >> (3 * (cc % 10))) & 7u;
        const uint32_t r3 = code & 3u, r2 = (code >> 2) & 1u;
        const uint32_t tgt = (cnt == 3u ? r3 : (cnt == 2u ? r2 : 0u)) + 1u;
        const int sel = (u0 == tgt) ? 0 : ((u0 + u1 == tgt) ? 1 : 2);
        const int to_add = (sel == 0) ? n0 : ((sel == 1) ? n1 : n2);
        const uint32_t wsel = (sel == 0) ? wd0 : ((sel == 1) ? wd1 : wd2);
        if (walker) {   // 2-lane mask; 2 stores, in-order DS within wave
          visW[(unsigned)to_add >> 5] = wsel | (1u << (to_add & 31));
          seqL[kw][cc + 1] = (uint16_t)to_add;
        }
        if (sel == 0)      { n0 = (int)(pA01 & 0xffffu); n1 = (int)(pA01 >> 16); n2 = (int)pA2; }
        else if (sel == 1) { n0 = (int)(pB01 & 0xffffu); n1 = (int)(pB01 >> 16); n2 = (int)pB2; }
        else               { n0 = (int)(pC01 & 0xffffu); n1 = (int)(pC01 >> 16); n2 = (int)pC2; }
        // prefetch next-iter rows + vis words (reads after this iter's
        // bitmap write: in-order DS per wave -> values fresh)
        pA01 = nb01L[n0]; pA2 = nb2L[n0];
        pB01 = nb01L[n1]; pB2 = nb2L[n1];
        pC01 = nb01L[n2]; pC2 = nb2L[n2];
        wd0 = visW[(unsigned)n0 >> 5];
        wd1 = visW[(unsigned)n1 >> 5];
        wd2 = visW[(unsigned)n2 >> 5];
      }
      const bool redo = walker && (sticky != 0u);
      if (__builtin_expect(__any(redo), 0)) {
        // ---- replay stuck walks from scratch via general loop ----
        if (redo) {
          for (int j = 0; j < VISW; ++j) visW[j] = 0u;
          visW[(unsigned)f0 >> 5] = 1u << (f0 & 31);
          seqL[kw][0] = (uint16_t)f0;
        }
        i = redo ? 1 : (L + 1);
        c = 0; bs = 1;
        const uint32_t pr0 = nb01L[f0];
        const uint32_t pr2v = nb2L[f0];
        if (redo) {
          n0 = (int)(pr0 & 0xffffu); n1 = (int)(pr0 >> 16); n2 = (int)pr2v;
        }
        pA01 = nb01L[n0]; pA2 = nb2L[n0];
        pB01 = nb01L[n1]; pB2 = nb2L[n1];
        pC01 = nb01L[n2]; pC2 = nb2L[n2];
        wd0 = visW[(unsigned)n0 >> 5];
        wd1 = visW[(unsigned)n1 >> 5];
        wd2 = visW[(unsigned)n2 >> 5];
      } else {
        do_general = false;
      }
    } else {
      i = walker ? 1 : (L + 1);
    }

    // ---------------- general loop (R12 body, verified) ------------------
    if (do_general) {
      for (;; ++c) {
        if (!__any(i <= L)) break;
        const bool act = (i <= L);

        const uint32_t u0 = ((wd0 >> (n0 & 31)) & 1u) ^ 1u;
        const uint32_t u1 = ((wd1 >> (n1 & 31)) & 1u) ^ 1u;
        const uint32_t u2 = ((wd2 >> (n2 & 31)) & 1u) ^ 1u;
        const uint32_t cnt = u0 + u1 + u2;

        uint32_t code;
        if (__builtin_expect(c < CH, 1)) {
          const int wi = c / 10;                    // uniform
          const int sh = 3 * (c - wi * 10);
          uint32_t cwv = cw[0];
          cwv = (wi == 1) ? cw[1] : cwv;  cwv = (wi == 2) ? cw[2] : cwv;
          cwv = (wi == 3) ? cw[3] : cwv;  cwv = (wi == 4) ? cw[4] : cwv;
          cwv = (wi == 5) ? cw[5] : cwv;  cwv = (wi == 6) ? cw[6] : cwv;
          code = (cwv >> sh) & 7u;
        } else {
          // live tree beyond cached steps (only after backtracks; uniform c)
          while (extc < c) { tf2x32(extka, extkb, 0u, 0u, extka, extkb); ++extc; }
          uint32_t k1a, k1b, hi, lo;
          tf2x32(extka, extkb, 0u, 1u, k1a, k1b);
          randbits(k1a, k1b, hi, lo);
          code = pick_code(hi, lo);
        }

        const bool need = act && (cnt == 0u);
        if (__builtin_expect(__any(need), 0)) {
          // ---- rare path (lane-local backtrack; bit-exact) ----
          while (extc < c) { tf2x32(extka, extkb, 0u, 0u, extka, extkb); ++extc; }
          const uint32_t kia = extka, kib = extkb;   // = k_c
          bool found = false; int ta = 0; int bsc = bs;
          if (need) {
            uint32_t kka, kkb;
            tf2x32(kia, kib, 0u, 2u, kka, kkb);      // k2
            while (!found && i > bsc) {
              uint32_t ca, cb, kpa, kpb;
              tf2x32(kka, kkb, 0u, 0u, ca, cb);
              tf2x32(kka, kkb, 0u, 1u, kpa, kpb);
              const int back = (int)seqL[kw][i - bsc - 1];
              const uint32_t pm = nb01L[back];
              const int m0 = (int)(pm & 0xffffu), m1 = (int)(pm >> 16);
              const int m2 = (int)nb2L[back];
              const uint32_t e0 = ((visW[(unsigned)m0 >> 5] >> (m0 & 31)) & 1u) ^ 1u;
              const uint32_t e1 = ((visW[(unsigned)m1 >> 5] >> (m1 & 31)) & 1u) ^ 1u;
              const uint32_t e2 = ((visW[(unsigned)m2 >> 5] >> (m2 & 31)) & 1u) ^ 1u;
              const uint32_t bc = e0 + e1 + e2;
              if (bc > 0) {
                uint32_t bhi, blo;
                randbits(kpa, kpb, bhi, blo);
                const uint32_t bcode = pick_code(bhi, blo);
                const uint32_t br3 = bcode & 3u, br2 = (bcode >> 2) & 1u;
                const uint32_t t2v = (bc == 3 ? br3 : (bc == 2 ? br2 : 0)) + 1;
                ta = (e0 == t2v) ? m0 : ((e0 + e1 == t2v) ? m1 : m2);
                found = true;
              } else {
                bsc += 2;
              }
              kka = ca; kkb = cb;
            }
          }
          int rnd = 0;
          if (need && !found) {
            uint32_t k3a, k3b, rhi, rlo;
            tf2x32(kia, kib, 0u, 3u, k3a, k3b);      // k3
            randbits(k3a, k3b, rhi, rlo);
            rnd = (int)r_generic(rhi, rlo, (uint32_t)N);
          }
          // common-path candidate for act && !need lanes
          const uint32_t r3 = code & 3u, r2 = (code >> 2) & 1u;
          const uint32_t tgt = (cnt == 3 ? r3 : (cnt == 2 ? r2 : 0)) + 1;
          const int selc = (u0 == tgt) ? 0 : ((u0 + u1 == tgt) ? 1 : 2);
          const int to_add_c = (selc == 0) ? n0 : ((selc == 1) ? n1 : n2);
          const uint32_t wselc = (selc == 0) ? wd0 : ((selc == 1) ? wd1 : wd2);

          const bool hit = need && found;
          const int to_add = need ? (found ? ta : rnd) : to_add_c;

          if (act) {
            uint32_t wdf = need ? visW[(unsigned)to_add >> 5] : wselc;
            visW[(unsigned)to_add >> 5] = wdf | (1u << (to_add & 31));
            if (hit) {
              const int i_new = i - bsc;
              for (int j = i_new; j < i; ++j) seqL[kw][j] = (uint16_t)to_add;
              bs = bsc; i = i_new + 1;
            } else {
              seqL[kw][i] = (uint16_t)to_add;
              bs = 1; ++i;
            }
          }
          // next candidates: dependent row read (rare)
          const int rn = act ? to_add : 0;
          const uint32_t pr = nb01L[rn];
          const uint32_t pr2 = nb2L[rn];
          if (act) {
            n0 = (int)(pr & 0xffffu); n1 = (int)(pr >> 16); n2 = (int)pr2;
          }
        } else {
          // ---- common path: branch-lean, fully lane-local ----
          const uint32_t r3 = code & 3u, r2 = (code >> 2) & 1u;
          const uint32_t tgt = (cnt == 3 ? r3 : (cnt == 2 ? r2 : 0)) + 1;
          const int sel = (u0 == tgt) ? 0 : ((u0 + u1 == tgt) ? 1 : 2);
          const int to_add = (sel == 0) ? n0 : ((sel == 1) ? n1 : n2);
          const uint32_t wsel = (sel == 0) ? wd0 : ((sel == 1) ? wd1 : wd2);
          if (act) {
            visW[(unsigned)to_add >> 5] = wsel | (1u << (to_add & 31));
            seqL[kw][i] = (uint16_t)to_add;
            bs = 1; ++i;
            if (sel == 0)      { n0 = (int)(pA01 & 0xffffu); n1 = (int)(pA01 >> 16); n2 = (int)pA2; }
            else if (sel == 1) { n0 = (int)(pB01 & 0xffffu); n1 = (int)(pB01 >> 16); n2 = (int)pB2; }
            else               { n0 = (int)(pC01 & 0xffffu); n1 = (int)(pC01 >> 16); n2 = (int)pC2; }
          }
        }
        // prefetch rows + vis words for next iteration
        pA01 = nb01L[n0]; pA2 = nb2L[n0];
        pB01 = nb01L[n1]; pB2 = nb2L[n1];
        pC01 = nb01L[n2]; pC2 = nb2L[n2];
        wd0 = visW[(unsigned)n0 >> 5];
        wd1 = visW[(unsigned)n1 >> 5];
        wd2 = visW[(unsigned)n2 >> 5];
      }
    }

    __syncthreads();   // barrier 5: all walks complete, seqL final

    // ---- Epilogue: block-wide gather-recenter from seqL -----------------
    const int items = WPB * Lp1;
    for (int idx = tid; idx < items; idx += THREADS) {
      const int wl = idx / Lp1;
      const int p = idx - wl * Lp1;
      const int ww = w0 + wl;
      if (ww < num_walks) {
        const int node = (int)seqL[wl][p];
        const float* xr = xb + 3 * (size_t)node;
        float3 v;
        v.x = xr[0] - cenL[wl][0];
        v.y = xr[1] - cenL[wl][1];
        v.z = xr[2] - cenL[wl][2];
        *reinterpret_cast<float3*>(out + ((size_t)ww * Lp1 + p) * 3) = v;
      }
    }
  } else {
    // ============ global-chase fallback (verified R5/R8/R10 logic) =======
    // 8 waves x 2 sequential full-wave walks; keys intact in visL scratch.
    for (int sub = 0; sub < 2; ++sub) {
      const int w = w0 + 2 * wv + sub;
      if (w >= num_walks) continue;          // wave-uniform
      const int bb = w / G;
      const int* __restrict__ nbG = nbrs + (size_t)bb * N * 3;
      const float* __restrict__ xb = xyz + (size_t)bb * N * 3;
      const int f0 = centers[w];
      const uint32_t mka = visL[((2 * wv + sub) * CH + lane) * 2 + 0];
      const uint32_t mkb = visL[((2 * wv + sub) * CH + lane) * 2 + 1];
      uint32_t mycode;
      {
        uint32_t k1a, k1b, hi, lo;
        tf2x32(mka, mkb, 0u, 1u, k1a, k1b);
        randbits(k1a, k1b, hi, lo);
        mycode = pick_code(hi, lo);
      }
      uint32_t extka = 0, extkb = 0;
      int extc = -1;
      auto get_key = [&](int idxk, uint32_t& ra, uint32_t& rb) {
        if (idxk < CH) {
          ra = (uint32_t)__shfl((int)mka, idxk);
          rb = (uint32_t)__shfl((int)mkb, idxk);
        } else {
          if (extc < 0) {
            extka = (uint32_t)__shfl((int)mka, CH - 1);
            extkb = (uint32_t)__shfl((int)mkb, CH - 1);
            extc = CH - 1;
          }
          while (extc < idxk) { tf2x32(extka, extkb, 0u, 0u, extka, extkb); ++extc; }
          ra = extka; rb = extkb;
        }
      };

      int seqr = (lane == 0) ? f0 : -1;
      uint32_t code_next = (uint32_t)__shfl((int)mycode, 0);
      int i = 1, bs = 1, c = 0;
      int hist  = (lane == 0) ? f0 : -1;
      int hist2 = -1;
      int3 row = *reinterpret_cast<const int3*>(nbG + 3 * (size_t)f0);
      while (i <= L) {
        const int idx = c; ++c;
        const bool deep = (idx >= CH);
        const uint32_t codeP = code_next;
        code_next = (uint32_t)__shfl((int)mycode, (c < CH) ? c : 0);

        const int n0 = row.x, n1 = row.y, n2 = row.z;
        int v0 = __any(hist == n0), v1 = __any(hist == n1), v2 = __any(hist == n2);
        if (deep) {
          v0 |= __any(hist2 == n0); v1 |= __any(hist2 == n1); v2 |= __any(hist2 == n2);
        }
        const int u0 = 1 - v0, u1 = 1 - v1, u2 = 1 - v2;
        const int cnt = u0 + u1 + u2;

        int to_add;
        bool hit = false;
        int bsf = bs;
        if (cnt > 0) {
          uint32_t code = codeP;
          if (deep) {
            uint32_t ia, ib, k1a, k1b, hi, lo;
            get_key(idx, ia, ib);
            tf2x32(ia, ib, 0u, 1u, k1a, k1b);
            randbits(k1a, k1b, hi, lo);
            code = pick_code(hi, lo);
          }
          const int r3 = (int)(code & 3u), r2 = (int)((code >> 2) & 1u);
          const int target = (cnt == 3 ? r3 : (cnt == 2 ? r2 : 0)) + 1;
          to_add = (u0 == target) ? n0 : ((u0 + u1 == target) ? n1 : n2);
        } else {
          uint32_t kia, kib;
          get_key(idx, kia, kib);
          uint32_t kka, kkb;
          tf2x32(kia, kib, 0u, 2u, kka, kkb);
          bool found = false;
          int ta = 0, bsc = bs;
          while (!found && i > bsc) {
            uint32_t ca, cb, kpa, kpb;
            tf2x32(kka, kkb, 0u, 0u, ca, cb);
            tf2x32(kka, kkb, 0u, 1u, kpa, kpb);
            const int back = __shfl(seqr, i - bsc - 1);
            const int3 br = *reinterpret_cast<const int3*>(nbG + 3 * (size_t)back);
            int w0m = __any(hist == br.x), w1m = __any(hist == br.y), w2m = __any(hist == br.z);
            if (deep) {
              w0m |= __any(hist2 == br.x); w1m |= __any(hist2 == br.y); w2m |= __any(hist2 == br.z);
            }
            const int e0 = 1 - w0m, e1 = 1 - w1m, e2 = 1 - w2m;
            const int bc = e0 + e1 + e2;
            if (bc > 0) {
              uint32_t bhi, blo;
              randbits(kpa, kpb, bhi, blo);
              const uint32_t bcode = pick_code(bhi, blo);
              const int r3 = (int)(bcode & 3u), r2 = (int)((bcode >> 2) & 1u);
              const int t2v = (bc == 3 ? r3 : (bc == 2 ? r2 : 0)) + 1;
              ta = (e0 == t2v) ? br.x : ((e0 + e1 == t2v) ? br.y : br.z);
              found = true;
            } else {
              bsc += 2;
            }
            kka = ca; kkb = cb;
          }
          if (found) {
            to_add = ta; hit = true; bsf = bsc;
          } else {
            uint32_t k3a, k3b, rhi, rlo;
            tf2x32(kia, kib, 0u, 3u, k3a, k3b);
            randbits(k3a, k3b, rhi, rlo);
            to_add = (int)r_generic(rhi, rlo, (uint32_t)N);
          }
        }

        int i_new, up;
        if (hit) { i_new = i - bsf; bs = bsf; up = i - 1; }
        else     { i_new = i;       bs = 1;   up = i; }
        seqr = (lane >= i_new && lane <= up) ? to_add : seqr;

        const int slot = idx + 1;
        if (slot < CH)          hist  = (lane == slot)      ? to_add : hist;
        else if (slot < 2 * CH) hist2 = (lane == slot - CH) ? to_add : hist2;

        i = i_new + 1;
        row = *reinterpret_cast<const int3*>(nbG + 3 * (size_t)to_add);
      }

      const float cx = xb[3 * (size_t)f0 + 0];
      const float cy = xb[3 * (size_t)f0 + 1];
      const float cz = xb[3 * (size_t)f0 + 2];
      if (lane < Lp1) {
        const int node = seqr;
        float3 v;
        v.x = xb[3 * (size_t)node + 0] - cx;
        v.y = xb[3 * (size_t)node + 1] - cy;
        v.z = xb[3 * (size_t)node + 2] - cz;
        *reinterpret_cast<float3*>(out + ((size_t)w * Lp1 + lane) * 3) = v;
      }
    }
  }
}

}  // namespace

extern "C" void kernel_launch(void* const* d_in, const int* in_sizes, int n_in,
                              void* d_out, int out_size, void* d_ws, size_t ws_size,
                              hipStream_t stream) {
  const float* xyz     = (const float*)d_in[0];
  const int*   nbrs    = (const int*)d_in[1];
  const int*   centers = (const int*)d_in[2];
  const int*   n_faces = (const int*)d_in[3];
  const int*   seq_len = (const int*)d_in[4];
  float* out = (float*)d_out;

  const int s0 = in_sizes[0];                  // B*N*3
  const int num_walks = in_sizes[2];           // B*G
  const int Lp1 = out_size / (3 * num_walks);  // seq_len+1

  const int blocks = (num_walks + WPB - 1) / WPB;
  walk_kernel<<<blocks, THREADS, 0, stream>>>(
      xyz, nbrs, centers, n_faces, seq_len, out, s0, num_walks, Lp1);
}

// Round 7
// 88.745 us; speedup vs baseline: 1.2508x; 1.0184x over previous
//
#include <hip/hip_runtime.h>
#include <stdint.h>
#include <stddef.h>

// MambaMesh random-walk + gather-recenter.  R15: DS-lean fast63 (11->6 ops).
// PRNG (bit-exact vs JAX partitionable Threefry, verified R1-R14, absmax 0.0):
//   split(key,n)[j]        = threefry2x32(key; 0, j)   (both output words)
//   random_bits(key,32,()) = xor-fold of threefry2x32(key; 0, 0)
// R14 post-mortem: unroll+debranch -> walk_kernel ~33us (out of top-5; fill
// kernels dominate profile). Walk ~20us = ~760cyc/iter vs DS-issue floor
// 11 ops x 8 waves x 5.8cyc ~= 510cyc -> the DS PIPE is the wall now.
// R15 cuts DS ops/iter 11->6: (a) read only the SELECTED row post-sel
// (2 reads) instead of prefetching all 3 candidate rows (6 reads) — the
// extra dependent round trip (~120cyc) hides under 2-waves/SIMD overlap;
// (b) seq moves to registers in the unrolled body (packed 2xu16/u32,
// compile-time indices only), dumped to seqL once after the loop.
// New floor ~280cyc/round. Stuck walks still replay via the verified
// general loop; L!=63 and !lds_ok paths unchanged.
//   block = 512 thr (8 waves), walker lanes 0/32, 16 walks/block, 256 blocks.
//   LDS: table 120,000 + bitmaps 40,000 + seq 2,176 + centers 192
//        = 162,368 B. Keys scratch visL[0..2047], codes visL[2048..2303].

namespace {

__device__ __forceinline__ uint32_t rotl32(uint32_t x, int r) {
  return (x << r) | (x >> (32 - r));
}

// Threefry-2x32, 20 rounds — exactly JAX's threefry2x32_p.
__device__ __forceinline__ void tf2x32(uint32_t ka, uint32_t kb,
                                       uint32_t x0, uint32_t x1,
                                       uint32_t& o0, uint32_t& o1) {
  const uint32_t kc = ka ^ kb ^ 0x1BD11BDAu;
  x0 += ka; x1 += kb;
#define TF_R4(r0, r1, r2, r3)                          \
  x0 += x1; x1 = rotl32(x1, r0); x1 ^= x0;             \
  x0 += x1; x1 = rotl32(x1, r1); x1 ^= x0;             \
  x0 += x1; x1 = rotl32(x1, r2); x1 ^= x0;             \
  x0 += x1; x1 = rotl32(x1, r3); x1 ^= x0;
  TF_R4(13, 15, 26, 6)  x0 += kb; x1 += kc + 1u;
  TF_R4(17, 29, 16, 24) x0 += kc; x1 += ka + 2u;
  TF_R4(13, 15, 26, 6)  x0 += ka; x1 += kb + 3u;
  TF_R4(17, 29, 16, 24) x0 += kb; x1 += kc + 4u;
  TF_R4(13, 15, 26, 6)  x0 += kc; x1 += ka + 5u;
#undef TF_R4
  o0 = x0; o1 = x1;
}

// (hi, lo) bits of jax.random.randint(key, (), 0, span): span-independent.
__device__ __forceinline__ void randbits(uint32_t ka, uint32_t kb,
                                         uint32_t& hi, uint32_t& lo) {
  uint32_t s0a, s0b, s1a, s1b, h0, h1;
  tf2x32(ka, kb, 0u, 0u, s0a, s0b);   // split(key)[0]
  tf2x32(ka, kb, 0u, 1u, s1a, s1b);   // split(key)[1]
  tf2x32(s0a, s0b, 0u, 0u, h0, h1);
  hi = h0 ^ h1;
  tf2x32(s1a, s1b, 0u, 0u, h0, h1);
  lo = h0 ^ h1;
}

__device__ __forceinline__ uint32_t r_generic(uint32_t hi, uint32_t lo,
                                              uint32_t span) {
  uint32_t mult = 65536u % span;
  mult = (mult * mult) % span;
  return ((hi % span) * mult + (lo % span)) % span;
}

// pick code: r3 (span=3 result) in bits 0..1, r2 (span=2 result) in bit 2.
__device__ __forceinline__ uint32_t pick_code(uint32_t hi, uint32_t lo) {
  return ((hi % 3u + lo % 3u) % 3u) | ((lo & 1u) << 2);
}

constexpr int WPB = 16;       // walks per block (2 per wave)
constexpr int CH = 64;        // cached chain length (covers seq_len 63)
constexpr int NMAX = 20000;   // LDS-table capacity (rows)
constexpr int VISW = 625;     // bitmap words per walk = ceil(NMAX/32)
constexpr int THREADS = 512;  // 8 waves

__global__ __launch_bounds__(512) void walk_kernel(
    const float* __restrict__ xyz, const int* __restrict__ nbrs,
    const int* __restrict__ centers, const int* __restrict__ n_faces_p,
    const int* __restrict__ seq_len_p, float* __restrict__ out,
    int s0, int num_walks, int Lp1) {
  // 80,000 + 40,000 + 40,000 + 2,176 + 192 = 162,368 B
  __shared__ uint32_t nb01L[NMAX];          // n0 | n1<<16
  __shared__ uint16_t nb2L[NMAX];           // n2
  __shared__ __align__(16) uint32_t visL[WPB * VISW];  // bitmaps; scratch
  __shared__ uint16_t seqL[WPB][CH + 4];    // +4 pad; row = 136 B (8-aligned)
  __shared__ float cenL[WPB][3];            // center xyz per walk

  const int tid = threadIdx.x;
  const int wv = tid >> 6, lane = tid & 63;
  const int w0 = blockIdx.x * WPB;
  if (w0 >= num_walks) return;               // block-uniform

  const int N = *n_faces_p;
  const int L = *seq_len_p;
  const int B = s0 / (3 * N);
  const int G = num_walks / B;
  const bool lds_ok = (N <= NMAX) && (G % WPB == 0) && (L < CH);
  const int bb0 = w0 / G;                    // all 16 walks share a batch

  // ---- Phase A: wave 0 lanes<16 = key carry chains -> visL[0..2047];
  //      waves 1..7 = table staging (lds_ok only). ------------------------
  if (wv == 0) {
    if (lane < WPB && (w0 + lane) < num_walks) {
      uint32_t ka, kb;
      tf2x32(0u, 42u, 0u, (uint32_t)(w0 + lane), ka, kb);  // k_0
      visL[(lane * CH + 0) * 2 + 0] = ka;
      visL[(lane * CH + 0) * 2 + 1] = kb;
#pragma clang loop unroll(disable)
      for (int c2 = 1; c2 < CH; ++c2) {
        tf2x32(ka, kb, 0u, 0u, ka, kb);
        visL[(lane * CH + c2) * 2 + 0] = ka;
        visL[(lane * CH + c2) * 2 + 1] = kb;
      }
    }
  } else if (lds_ok) {
    const int* __restrict__ nbT = nbrs + (size_t)bb0 * N * 3;
    for (int r = tid - 64; r < N; r += (THREADS - 64)) {
      const int3 v = *reinterpret_cast<const int3*>(nbT + 3 * (size_t)r);
      nb01L[r] = (uint32_t)v.x | ((uint32_t)v.y << 16);
      nb2L[r]  = (uint16_t)v.z;
    }
  }
  __syncthreads();   // barrier 1: keys + table staged

  if (lds_ok) {
    const float* __restrict__ xb = xyz + (size_t)bb0 * N * 3;
    // ---- Phase B: per-step codes, (walk,step) pairs over all threads ----
    uint8_t* const codesB = reinterpret_cast<uint8_t*>(&visL[2048]);
#pragma unroll
    for (int p = 0; p < (WPB * CH) / THREADS; ++p) {   // 2 pairs/thread
      const int pair = tid + THREADS * p;
      const int wk = pair >> 6, st = pair & 63;
      if ((w0 + wk) < num_walks) {
        const uint32_t ka = visL[(wk * CH + st) * 2 + 0];
        const uint32_t kb = visL[(wk * CH + st) * 2 + 1];
        uint32_t k1a, k1b, hi, lo;
        tf2x32(ka, kb, 0u, 1u, k1a, k1b);   // k1 = split(k,4)[1]
        randbits(k1a, k1b, hi, lo);
        codesB[wk * CH + st] = (uint8_t)pick_code(hi, lo);
      }
    }
    // centers -> cenL (16 threads; overlaps codes work of others)
    if (tid < WPB && (w0 + tid) < num_walks) {
      const int f0t = centers[w0 + tid];
      cenL[tid][0] = xb[3 * (size_t)f0t + 0];
      cenL[tid][1] = xb[3 * (size_t)f0t + 1];
      cenL[tid][2] = xb[3 * (size_t)f0t + 2];
    }
    __syncthreads();   // barrier 2: codes + centers ready

    // ---- Phase C: walker lanes (0 and 32 of each wave) pack codes -------
    const int kw = 2 * wv + (lane >> 5);     // walk slot for this half
    const int w = w0 + kw;
    const bool walker = ((lane & 31) == 0) && (w < num_walks);
    uint32_t cw[7] = {0, 0, 0, 0, 0, 0, 0};
    uint32_t k0a = 0, k0b = 0;
    if (walker) {
      tf2x32(0u, 42u, 0u, (uint32_t)w, k0a, k0b);   // cheap k_0 recompute
      const uint32_t* cwd = &visL[2048 + kw * (CH / 4)];
#pragma unroll
      for (int t = 0; t < CH / 4; ++t) {
        const uint32_t wd = cwd[t];
#pragma unroll
        for (int b = 0; b < 4; ++b) {
          const int s = 4 * t + b;               // compile-time
          const uint32_t c3 = (wd >> (8 * b)) & 7u;
          cw[s / 10] |= c3 << (3 * (s % 10));    // constant indices only
        }
      }
    }
    __syncthreads();   // barrier 3: scratch reads done
    // ---- Phase D: zero bitmaps (b128; visL is 16B-aligned, 2500 uint4) --
    {
      uint4* const v4 = reinterpret_cast<uint4*>(visL);
      const uint4 z = make_uint4(0u, 0u, 0u, 0u);
      for (int j = tid; j < (WPB * VISW) / 4; j += THREADS) v4[j] = z;
    }
    __syncthreads();   // barrier 4: bitmaps ready

    // =================== 8 waves x 2 lane-local walks ====================
    const int f0 = walker ? centers[w] : 0;
    uint32_t* __restrict__ visW = visL + (walker ? kw : 0) * VISW;

    if (walker) {
      visW[(unsigned)f0 >> 5] = 1u << (f0 & 31);
      seqL[kw][0] = (uint16_t)f0;
    }

    // candidate state + vis prefetch (rows of candidates NOT prefetched
    // in the fast path; general loop sets up its own prefetch)
    const uint32_t p0 = nb01L[f0];
    int n0 = (int)(p0 & 0xffffu), n1 = (int)(p0 >> 16), n2 = (int)nb2L[f0];
    uint32_t wd0 = visW[(unsigned)n0 >> 5];
    uint32_t wd1 = visW[(unsigned)n1 >> 5];
    uint32_t wd2 = visW[(unsigned)n2 >> 5];
    uint32_t pA01, pB01, pC01, pA2, pB2, pC2;   // general-loop prefetch regs

    int extc = 0; uint32_t extka = k0a, extkb = k0b;   // extka = k_extc
    int c = 0, bs = 1;
    int i = L + 1;              // default: inactive in general loop
    bool do_general = true;

    if (L == 63) {
      // ------- fully unrolled branchless DS-lean fast path (63 steps) ----
      uint32_t sticky = 0u;
      uint32_t sp[32];                       // packed seq: 2 x u16 per u32
#pragma unroll
      for (int j = 0; j < 32; ++j) sp[j] = 0u;
      sp[0] = (uint32_t)f0 & 0xffffu;        // entry 0
#pragma clang loop unroll(full)
      for (int cc = 0; cc < 63; ++cc) {
        const uint32_t u0 = ((wd0 >> (n0 & 31)) & 1u) ^ 1u;
        const uint32_t u1 = ((wd1 >> (n1 & 31)) & 1u) ^ 1u;
        const uint32_t u2 = ((wd2 >> (n2 & 31)) & 1u) ^ 1u;
        const uint32_t cnt = u0 + u1 + u2;
        sticky |= (cnt == 0u) ? 1u : 0u;           // no branch; junk-safe
        // cc compile-time -> single register read, no ladder/div
        const uint32_t code = (cw[cc / 10] >> (3 * (cc % 10))) & 7u;
        const uint32_t r3 = code & 3u, r2 = (code >> 2) & 1u;
        const uint32_t tgt = (cnt == 3u ? r3 : (cnt == 2u ? r2 : 0u)) + 1u;
        const int sel = (u0 == tgt) ? 0 : ((u0 + u1 == tgt) ? 1 : 2);
        const int to_add = (sel == 0) ? n0 : ((sel == 1) ? n1 : n2);
        const uint32_t wsel = (sel == 0) ? wd0 : ((sel == 1) ? wd1 : wd2);
        if (walker) {   // 2-lane mask; 1 store, in-order DS within wave
          visW[(unsigned)to_add >> 5] = wsel | (1u << (to_add & 31));
        }
        // seq -> registers (compile-time index; no LDS write in loop)
        sp[(cc + 1) >> 1] |= (uint32_t)to_add << (16 * ((cc + 1) & 1));
        // dependent SELECTED-row read (2 DS ops, replaces 6-op prefetch)
        const uint32_t pr01 = nb01L[to_add];
        const uint32_t pr2v = nb2L[to_add];
        n0 = (int)(pr01 & 0xffffu); n1 = (int)(pr01 >> 16); n2 = (int)pr2v;
        // vis words for next iter (read after this iter's write: in-order)
        wd0 = visW[(unsigned)n0 >> 5];
        wd1 = visW[(unsigned)n1 >> 5];
        wd2 = visW[(unsigned)n2 >> 5];
      }
      // dump register seq -> seqL (one-time; row is 4B-aligned, 136 B)
      if (walker) {
        uint32_t* rowp = reinterpret_cast<uint32_t*>(&seqL[kw][0]);
#pragma unroll
        for (int j = 0; j < 32; ++j) rowp[j] = sp[j];
      }
      const bool redo = walker && (sticky != 0u);
      if (__builtin_expect(__any(redo), 0)) {
        // ---- replay stuck walks from scratch via general loop ----
        if (redo) {
          for (int j = 0; j < VISW; ++j) visW[j] = 0u;
          visW[(unsigned)f0 >> 5] = 1u << (f0 & 31);
          seqL[kw][0] = (uint16_t)f0;
        }
        i = redo ? 1 : (L + 1);
        c = 0; bs = 1;
        const uint32_t pr0 = nb01L[f0];
        const uint32_t pr2v = nb2L[f0];
        if (redo) {
          n0 = (int)(pr0 & 0xffffu); n1 = (int)(pr0 >> 16); n2 = (int)pr2v;
        }
      } else {
        do_general = false;
      }
    } else {
      i = walker ? 1 : (L + 1);
    }

    // ---------------- general loop (R12 body, verified) ------------------
    if (do_general) {
      // (re)establish candidate-row + vis prefetch for the general loop
      pA01 = nb01L[n0]; pA2 = nb2L[n0];
      pB01 = nb01L[n1]; pB2 = nb2L[n1];
      pC01 = nb01L[n2]; pC2 = nb2L[n2];
      wd0 = visW[(unsigned)n0 >> 5];
      wd1 = visW[(unsigned)n1 >> 5];
      wd2 = visW[(unsigned)n2 >> 5];
      for (;; ++c) {
        if (!__any(i <= L)) break;
        const bool act = (i <= L);

        const uint32_t u0 = ((wd0 >> (n0 & 31)) & 1u) ^ 1u;
        const uint32_t u1 = ((wd1 >> (n1 & 31)) & 1u) ^ 1u;
        const uint32_t u2 = ((wd2 >> (n2 & 31)) & 1u) ^ 1u;
        const uint32_t cnt = u0 + u1 + u2;

        uint32_t code;
        if (__builtin_expect(c < CH, 1)) {
          const int wi = c / 10;                    // uniform
          const int sh = 3 * (c - wi * 10);
          uint32_t cwv = cw[0];
          cwv = (wi == 1) ? cw[1] : cwv;  cwv = (wi == 2) ? cw[2] : cwv;
          cwv = (wi == 3) ? cw[3] : cwv;  cwv = (wi == 4) ? cw[4] : cwv;
          cwv = (wi == 5) ? cw[5] : cwv;  cwv = (wi == 6) ? cw[6] : cwv;
          code = (cwv >> sh) & 7u;
        } else {
          // live tree beyond cached steps (only after backtracks; uniform c)
          while (extc < c) { tf2x32(extka, extkb, 0u, 0u, extka, extkb); ++extc; }
          uint32_t k1a, k1b, hi, lo;
          tf2x32(extka, extkb, 0u, 1u, k1a, k1b);
          randbits(k1a, k1b, hi, lo);
          code = pick_code(hi, lo);
        }

        const bool need = act && (cnt == 0u);
        if (__builtin_expect(__any(need), 0)) {
          // ---- rare path (lane-local backtrack; bit-exact) ----
          while (extc < c) { tf2x32(extka, extkb, 0u, 0u, extka, extkb); ++extc; }
          const uint32_t kia = extka, kib = extkb;   // = k_c
          bool found = false; int ta = 0; int bsc = bs;
          if (need) {
            uint32_t kka, kkb;
            tf2x32(kia, kib, 0u, 2u, kka, kkb);      // k2
            while (!found && i > bsc) {
              uint32_t ca, cb, kpa, kpb;
              tf2x32(kka, kkb, 0u, 0u, ca, cb);
              tf2x32(kka, kkb, 0u, 1u, kpa, kpb);
              const int back = (int)seqL[kw][i - bsc - 1];
              const uint32_t pm = nb01L[back];
              const int m0 = (int)(pm & 0xffffu), m1 = (int)(pm >> 16);
              const int m2 = (int)nb2L[back];
              const uint32_t e0 = ((visW[(unsigned)m0 >> 5] >> (m0 & 31)) & 1u) ^ 1u;
              const uint32_t e1 = ((visW[(unsigned)m1 >> 5] >> (m1 & 31)) & 1u) ^ 1u;
              const uint32_t e2 = ((visW[(unsigned)m2 >> 5] >> (m2 & 31)) & 1u) ^ 1u;
              const uint32_t bc = e0 + e1 + e2;
              if (bc > 0) {
                uint32_t bhi, blo;
                randbits(kpa, kpb, bhi, blo);
                const uint32_t bcode = pick_code(bhi, blo);
                const uint32_t br3 = bcode & 3u, br2 = (bcode >> 2) & 1u;
                const uint32_t t2v = (bc == 3 ? br3 : (bc == 2 ? br2 : 0)) + 1;
                ta = (e0 == t2v) ? m0 : ((e0 + e1 == t2v) ? m1 : m2);
                found = true;
              } else {
                bsc += 2;
              }
              kka = ca; kkb = cb;
            }
          }
          int rnd = 0;
          if (need && !found) {
            uint32_t k3a, k3b, rhi, rlo;
            tf2x32(kia, kib, 0u, 3u, k3a, k3b);      // k3
            randbits(k3a, k3b, rhi, rlo);
            rnd = (int)r_generic(rhi, rlo, (uint32_t)N);
          }
          // common-path candidate for act && !need lanes
          const uint32_t r3 = code & 3u, r2 = (code >> 2) & 1u;
          const uint32_t tgt = (cnt == 3 ? r3 : (cnt == 2 ? r2 : 0)) + 1;
          const int selc = (u0 == tgt) ? 0 : ((u0 + u1 == tgt) ? 1 : 2);
          const int to_add_c = (selc == 0) ? n0 : ((selc == 1) ? n1 : n2);
          const uint32_t wselc = (selc == 0) ? wd0 : ((selc == 1) ? wd1 : wd2);

          const bool hit = need && found;
          const int to_add = need ? (found ? ta : rnd) : to_add_c;

          if (act) {
            uint32_t wdf = need ? visW[(unsigned)to_add >> 5] : wselc;
            visW[(unsigned)to_add >> 5] = wdf | (1u << (to_add & 31));
            if (hit) {
              const int i_new = i - bsc;
              for (int j = i_new; j < i; ++j) seqL[kw][j] = (uint16_t)to_add;
              bs = bsc; i = i_new + 1;
            } else {
              seqL[kw][i] = (uint16_t)to_add;
              bs = 1; ++i;
            }
          }
          // next candidates: dependent row read (rare)
          const int rn = act ? to_add : 0;
          const uint32_t pr = nb01L[rn];
          const uint32_t pr2 = nb2L[rn];
          if (act) {
            n0 = (int)(pr & 0xffffu); n1 = (int)(pr >> 16); n2 = (int)pr2;
          }
        } else {
          // ---- common path: branch-lean, fully lane-local ----
          const uint32_t r3 = code & 3u, r2 = (code >> 2) & 1u;
          const uint32_t tgt = (cnt == 3 ? r3 : (cnt == 2 ? r2 : 0)) + 1;
          const int sel = (u0 == tgt) ? 0 : ((u0 + u1 == tgt) ? 1 : 2);
          const int to_add = (sel == 0) ? n0 : ((sel == 1) ? n1 : n2);
          const uint32_t wsel = (sel == 0) ? wd0 : ((sel == 1) ? wd1 : wd2);
          if (act) {
            visW[(unsigned)to_add >> 5] = wsel | (1u << (to_add & 31));
            seqL[kw][i] = (uint16_t)to_add;
            bs = 1; ++i;
            if (sel == 0)      { n0 = (int)(pA01 & 0xffffu); n1 = (int)(pA01 >> 16); n2 = (int)pA2; }
            else if (sel == 1) { n0 = (int)(pB01 & 0xffffu); n1 = (int)(pB01 >> 16); n2 = (int)pB2; }
            else               { n0 = (int)(pC01 & 0xffffu); n1 = (int)(pC01 >> 16); n2 = (int)pC2; }
          }
        }
        // prefetch rows + vis words for next iteration
        pA01 = nb01L[n0]; pA2 = nb2L[n0];
        pB01 = nb01L[n1]; pB2 = nb2L[n1];
        pC01 = nb01L[n2]; pC2 = nb2L[n2];
        wd0 = visW[(unsigned)n0 >> 5];
        wd1 = visW[(unsigned)n1 >> 5];
        wd2 = visW[(unsigned)n2 >> 5];
      }
    }

    __syncthreads();   // barrier 5: all walks complete, seqL final

    // ---- Epilogue: block-wide gather-recenter from seqL -----------------
    const int items = WPB * Lp1;
    for (int idx = tid; idx < items; idx += THREADS) {
      const int wl = idx / Lp1;
      const int p = idx - wl * Lp1;
      const int ww = w0 + wl;
      if (ww < num_walks) {
        const int node = (int)seqL[wl][p];
        const float* xr = xb + 3 * (size_t)node;
        float3 v;
        v.x = xr[0] - cenL[wl][0];
        v.y = xr[1] - cenL[wl][1];
        v.z = xr[2] - cenL[wl][2];
        *reinterpret_cast<float3*>(out + ((size_t)ww * Lp1 + p) * 3) = v;
      }
    }
  } else {
    // ============ global-chase fallback (verified R5/R8/R10 logic) =======
    // 8 waves x 2 sequential full-wave walks; keys intact in visL scratch.
    for (int sub = 0; sub < 2; ++sub) {
      const int w = w0 + 2 * wv + sub;
      if (w >= num_walks) continue;          // wave-uniform
      const int bb = w / G;
      const int* __restrict__ nbG = nbrs + (size_t)bb * N * 3;
      const float* __restrict__ xb = xyz + (size_t)bb * N * 3;
      const int f0 = centers[w];
      const uint32_t mka = visL[((2 * wv + sub) * CH + lane) * 2 + 0];
      const uint32_t mkb = visL[((2 * wv + sub) * CH + lane) * 2 + 1];
      uint32_t mycode;
      {
        uint32_t k1a, k1b, hi, lo;
        tf2x32(mka, mkb, 0u, 1u, k1a, k1b);
        randbits(k1a, k1b, hi, lo);
        mycode = pick_code(hi, lo);
      }
      uint32_t extka = 0, extkb = 0;
      int extc = -1;
      auto get_key = [&](int idxk, uint32_t& ra, uint32_t& rb) {
        if (idxk < CH) {
          ra = (uint32_t)__shfl((int)mka, idxk);
          rb = (uint32_t)__shfl((int)mkb, idxk);
        } else {
          if (extc < 0) {
            extka = (uint32_t)__shfl((int)mka, CH - 1);
            extkb = (uint32_t)__shfl((int)mkb, CH - 1);
            extc = CH - 1;
          }
          while (extc < idxk) { tf2x32(extka, extkb, 0u, 0u, extka, extkb); ++extc; }
          ra = extka; rb = extkb;
        }
      };

      int seqr = (lane == 0) ? f0 : -1;
      uint32_t code_next = (uint32_t)__shfl((int)mycode, 0);
      int i = 1, bs = 1, c = 0;
      int hist  = (lane == 0) ? f0 : -1;
      int hist2 = -1;
      int3 row = *reinterpret_cast<const int3*>(nbG + 3 * (size_t)f0);
      while (i <= L) {
        const int idx = c; ++c;
        const bool deep = (idx >= CH);
        const uint32_t codeP = code_next;
        code_next = (uint32_t)__shfl((int)mycode, (c < CH) ? c : 0);

        const int n0 = row.x, n1 = row.y, n2 = row.z;
        int v0 = __any(hist == n0), v1 = __any(hist == n1), v2 = __any(hist == n2);
        if (deep) {
          v0 |= __any(hist2 == n0); v1 |= __any(hist2 == n1); v2 |= __any(hist2 == n2);
        }
        const int u0 = 1 - v0, u1 = 1 - v1, u2 = 1 - v2;
        const int cnt = u0 + u1 + u2;

        int to_add;
        bool hit = false;
        int bsf = bs;
        if (cnt > 0) {
          uint32_t code = codeP;
          if (deep) {
            uint32_t ia, ib, k1a, k1b, hi, lo;
            get_key(idx, ia, ib);
            tf2x32(ia, ib, 0u, 1u, k1a, k1b);
            randbits(k1a, k1b, hi, lo);
            code = pick_code(hi, lo);
          }
          const int r3 = (int)(code & 3u), r2 = (int)((code >> 2) & 1u);
          const int target = (cnt == 3 ? r3 : (cnt == 2 ? r2 : 0)) + 1;
          to_add = (u0 == target) ? n0 : ((u0 + u1 == target) ? n1 : n2);
        } else {
          uint32_t kia, kib;
          get_key(idx, kia, kib);
          uint32_t kka, kkb;
          tf2x32(kia, kib, 0u, 2u, kka, kkb);
          bool found = false;
          int ta = 0, bsc = bs;
          while (!found && i > bsc) {
            uint32_t ca, cb, kpa, kpb;
            tf2x32(kka, kkb, 0u, 0u, ca, cb);
            tf2x32(kka, kkb, 0u, 1u, kpa, kpb);
            const int back = __shfl(seqr, i - bsc - 1);
            const int3 br = *reinterpret_cast<const int3*>(nbG + 3 * (size_t)back);
            int w0m = __any(hist == br.x), w1m = __any(hist == br.y), w2m = __any(hist == br.z);
            if (deep) {
              w0m |= __any(hist2 == br.x); w1m |= __any(hist2 == br.y); w2m |= __any(hist2 == br.z);
            }
            const int e0 = 1 - w0m, e1 = 1 - w1m, e2 = 1 - w2m;
            const int bc = e0 + e1 + e2;
            if (bc > 0) {
              uint32_t bhi, blo;
              randbits(kpa, kpb, bhi, blo);
              const uint32_t bcode = pick_code(bhi, blo);
              const int r3 = (int)(bcode & 3u), r2 = (int)((bcode >> 2) & 1u);
              const int t2v = (bc == 3 ? r3 : (bc == 2 ? r2 : 0)) + 1;
              ta = (e0 == t2v) ? br.x : ((e0 + e1 == t2v) ? br.y : br.z);
              found = true;
            } else {
              bsc += 2;
            }
            kka = ca; kkb = cb;
          }
          if (found) {
            to_add = ta; hit = true; bsf = bsc;
          } else {
            uint32_t k3a, k3b, rhi, rlo;
            tf2x32(kia, kib, 0u, 3u, k3a, k3b);
            randbits(k3a, k3b, rhi, rlo);
            to_add = (int)r_generic(rhi, rlo, (uint32_t)N);
          }
        }

        int i_new, up;
        if (hit) { i_new = i - bsf; bs = bsf; up = i - 1; }
        else     { i_new = i;       bs = 1;   up = i; }
        seqr = (lane >= i_new && lane <= up) ? to_add : seqr;

        const int slot = idx + 1;
        if (slot < CH)          hist  = (lane == slot)      ? to_add : hist;
        else if (slot < 2 * CH) hist2 = (lane == slot - CH) ? to_add : hist2;

        i = i_new + 1;
        row = *reinterpret_cast<const int3*>(nbG + 3 * (size_t)to_add);
      }

      const float cx = xb[3 * (size_t)f0 + 0];
      const float cy = xb[3 * (size_t)f0 + 1];
      const float cz = xb[3 * (size_t)f0 + 2];
      if (lane < Lp1) {
        const int node = seqr;
        float3 v;
        v.x = xb[3 * (size_t)node + 0] - cx;
        v.y = xb[3 * (size_t)node + 1] - cy;
        v.z = xb[3 * (size_t)node + 2] - cz;
        *reinterpret_cast<float3*>(out + ((size_t)w * Lp1 + lane) * 3) = v;
      }
    }
  }
}

}  // namespace

extern "C" void kernel_launch(void* const* d_in, const int* in_sizes, int n_in,
                              void* d_out, int out_size, void* d_ws, size_t ws_size,
                              hipStream_t stream) {
  const float* xyz     = (const float*)d_in[0];
  const int*   nbrs    = (const int*)d_in[1];
  const int*   centers = (const int*)d_in[2];
  const int*   n_faces = (const int*)d_in[3];
  const int*   seq_len = (const int*)d_in[4];
  float* out = (float*)d_out;

  const int s0 = in_sizes[0];                  // B*N*3
  const int num_walks = in_sizes[2];           // B*G
  const int Lp1 = out_size / (3 * num_walks);  // seq_len+1

  const int blocks = (num_walks + WPB - 1) / WPB;
  walk_kernel<<<blocks, THREADS, 0, stream>>>(
      xyz, nbrs, centers, n_faces, seq_len, out, s0, num_walks, Lp1);
}